// Round 10
// baseline (178.967 us; speedup 1.0000x reference)
//
#include <hip/hip_runtime.h>
#include <stdint.h>

#define NB 4
#define NH 16
#define DKH 64
#define DMODEL 1024
#define SEQ 1024
#define SCALE 0.125f
#define NEG_INF -1.0e9f
#define K2E 0.18033688011112042f  // SCALE * log2(e): softmax in exp2 domain

typedef __bf16 bf16_t;
typedef __bf16 bf16x8 __attribute__((ext_vector_type(8)));
typedef __bf16 bf16x4v __attribute__((ext_vector_type(4)));
typedef float f32x4 __attribute__((ext_vector_type(4)));
typedef float f32x16 __attribute__((ext_vector_type(16)));
typedef uint32_t u32x4 __attribute__((ext_vector_type(4)));

typedef const uint32_t __attribute__((address_space(1)))* gas_ptr;
typedef uint32_t __attribute__((address_space(3)))* las_ptr;

// async global->LDS, 16B per lane, dest = wave-uniform base + lane*16
__device__ __forceinline__ void gload_lds16(const void* g, void* l) {
  __builtin_amdgcn_global_load_lds((gas_ptr)g, (las_ptr)l, 16, 0, 0);
}

__device__ __forceinline__ f32x16 z16() {
  f32x16 v;
#pragma unroll
  for (int i = 0; i < 16; ++i) v[i] = 0.f;
  return v;
}

// pack 2 f32 -> 1 dword of 2 bf16 (lo in low half)
__device__ __forceinline__ uint32_t cvtpk_bf16(float lo, float hi) {
  uint32_t r;
  asm("v_cvt_pk_bf16_f32 %0, %1, %2" : "=v"(r) : "v"(lo), "v"(hi));
  return r;
}
// upper 32 lanes of a <-> lower 32 lanes of b
__device__ __forceinline__ void plane32_swap(uint32_t& a, uint32_t& b) {
  asm("v_permlane32_swap_b32 %0, %1" : "+v"(a), "+v"(b));
}

// T2 XOR swizzle for [R][64] bf16 tiles: element col ^= (row&7)<<3; staging
// keeps LDS dest linear and pre-swizzles the GLOBAL source column.
// Journal: R2 swizzle: conflicts 1.99e7->0. R4 (256,4)->spill; (256,2) sane.
// R6 vis/rel reg-interleave HURT. R7 32q/wave shared frags: ->77.9us (best).
// R8 branch-split + R9 2-phase/dbuf/VALU-diet: both regressed -> reverted.
// R10: 32x32 MFMA + in-register P via cvt_pk + permlane32_swap (T12) --
// removes P LDS round-trip + its bank conflicts + 16KB LDS.

// ---------------- f32 -> bf16 conversion (select tensor by blockIdx.y) ----
__global__ void cvt_multi(const float* __restrict__ i0, const float* __restrict__ i1,
                          const float* __restrict__ i2, const float* __restrict__ i3,
                          const float* __restrict__ i4, const float* __restrict__ i5,
                          bf16_t* o0, bf16_t* o1, bf16_t* o2, bf16_t* o3, bf16_t* o4, bf16_t* o5,
                          int n) {
  const int t = blockIdx.y;
  const float* in = (t == 0) ? i0 : (t == 1) ? i1 : (t == 2) ? i2 : (t == 3) ? i3 : (t == 4) ? i4 : i5;
  bf16_t* out = (t == 0) ? o0 : (t == 1) ? o1 : (t == 2) ? o2 : (t == 3) ? o3 : (t == 4) ? o4 : o5;
  const int idx = (blockIdx.x * 256 + threadIdx.x) * 4;
  if (idx >= n) return;
  const float4 v = *(const float4*)(in + idx);
  bf16x4v p;
  p[0] = (bf16_t)v.x; p[1] = (bf16_t)v.y; p[2] = (bf16_t)v.z; p[3] = (bf16_t)v.w;
  *(bf16x4v*)(out + idx) = p;
}

// ---------------- 128x128-tile GEMM core (m97 structure) -------------------
#define NXE ((size_t)NB * SEQ * DMODEL)      // elements per X/out segment
#define NWE ((size_t)DMODEL * DMODEL)

template<int MODE>
__device__ __forceinline__ void gemm128_body(
    const bf16_t* __restrict__ A, const bf16_t* __restrict__ W,
    const float* __restrict__ bias, void* __restrict__ outp,
    int m0, int n0, bf16_t* As, bf16_t* Bs) {
  const int tid = threadIdx.x;
  const int lane = tid & 63;
  const int w = tid >> 6;
  const int wm = w >> 1, wn = w & 1;
  const int g = lane >> 4, c = lane & 15;
  const int lrow = lane >> 3;
  const int lcol = ((lane & 7) * 8) ^ ((lane >> 3) << 3);  // pre-swizzled source col
  const int sc = (c & 7) << 3;                             // read-side XOR

  f32x4 acc[4][4] = {};

  for (int kt = 0; kt < DMODEL; kt += 64) {
#pragma unroll
    for (int p = 0; p < 4; ++p) {
      const int row = w * 32 + p * 8;
      gload_lds16(A + (size_t)(m0 + row + lrow) * DMODEL + kt + lcol, &As[row * 64]);
      gload_lds16(W + (size_t)(n0 + row + lrow) * DMODEL + kt + lcol, &Bs[row * 64]);
    }
    __syncthreads();
    bf16x8 af[4][2], bfr[4][2];
#pragma unroll
    for (int i = 0; i < 4; ++i)
#pragma unroll
      for (int kk = 0; kk < 2; ++kk) {
        af[i][kk]  = *(const bf16x8*)&As[(wm * 64 + i * 16 + c) * 64 + ((kk * 32 + g * 8) ^ sc)];
        bfr[i][kk] = *(const bf16x8*)&Bs[(wn * 64 + i * 16 + c) * 64 + ((kk * 32 + g * 8) ^ sc)];
      }
#pragma unroll
    for (int i = 0; i < 4; ++i)
#pragma unroll
      for (int j = 0; j < 4; ++j) {
        acc[i][j] = __builtin_amdgcn_mfma_f32_16x16x32_bf16(af[i][0], bfr[j][0], acc[i][j], 0, 0, 0);
        acc[i][j] = __builtin_amdgcn_mfma_f32_16x16x32_bf16(af[i][1], bfr[j][1], acc[i][j], 0, 0, 0);
      }
    __syncthreads();
  }

  float bv4[4];
#pragma unroll
  for (int j = 0; j < 4; ++j) bv4[j] = bias[n0 + wn * 64 + j * 16 + c];

#pragma unroll
  for (int i = 0; i < 4; ++i) {
    const int mrow = m0 + wm * 64 + i * 16 + g * 4;   // C-layout: row = g*4 + r
    const int b_ = mrow >> 10, l_ = mrow & 1023;
#pragma unroll
    for (int j = 0; j < 4; ++j) {
      const int n = n0 + wn * 64 + j * 16 + c;        // C-layout: col = lane&15
      if (MODE == 2) {
        float* o = (float*)outp;
#pragma unroll
        for (int r = 0; r < 4; ++r)
          o[(size_t)(mrow + r) * DMODEL + n] = acc[i][j][r] + bv4[j];
      } else if (MODE == 0) {
        bf16_t* o = (bf16_t*)outp;
        const int h_ = n >> 6, dk_ = n & 63;
#pragma unroll
        for (int r = 0; r < 4; ++r)
          o[((size_t)(b_ * NH + h_) * SEQ + l_ + r) * DKH + dk_] =
              (bf16_t)(acc[i][j][r] + bv4[j]);
      } else { // MODE 1: transposed [B,H,DK,L]; 4 consecutive l -> packed 8B store
        bf16_t* o = (bf16_t*)outp;
        const int h_ = n >> 6, dk_ = n & 63;
        bf16x4v pk;
#pragma unroll
        for (int r = 0; r < 4; ++r) pk[r] = (bf16_t)(acc[i][j][r] + bv4[j]);
        *(bf16x4v*)&o[((size_t)(b_ * NH + h_) * DKH + dk_) * SEQ + l_] = pk;
      }
    }
  }
}

// grouped projection: 5 segments x (32 m-tiles x 8 n-tiles) = 1280 blocks
__global__ void __launch_bounds__(256, 2)
proj_gemm(const bf16_t* __restrict__ Xbase, const bf16_t* __restrict__ Wbase,
          bf16_t* __restrict__ Obase,
          const float* __restrict__ b0, const float* __restrict__ b1,
          const float* __restrict__ b2, const float* __restrict__ b3,
          const float* __restrict__ b4) {
  __shared__ bf16_t As[128 * 64];
  __shared__ bf16_t Bs[128 * 64];
  const int bid = blockIdx.x;
  const int lid = (bid & 7) * 160 + (bid >> 3);   // T1 swizzle (1280 % 8 == 0)
  const int seg = lid >> 8;                       // 0..4
  const int rr = lid & 255;
  const int m0 = (rr >> 3) * 128, n0 = (rr & 7) * 128;

  const bf16_t* A = Xbase + (size_t)((seg < 3) ? seg : 3) * NXE;
  const bf16_t* W = Wbase + (size_t)seg * NWE;
  const int ooff = (seg == 0) ? 0 : (seg == 1) ? 1 : (seg == 2) ? 3 : (seg == 3) ? 2 : 4;
  bf16_t* out = Obase + (size_t)ooff * NXE;
  const float* bias = (seg == 0) ? b0 : (seg == 1) ? b1 : (seg == 2) ? b2 : (seg == 3) ? b3 : b4;

  if (seg == 2 || seg == 4) gemm128_body<1>(A, W, bias, out, m0, n0, As, Bs);
  else                      gemm128_body<0>(A, W, bias, out, m0, n0, As, Bs);
}

// output projection -> f32 d_out: 32 x 8 = 256 blocks
__global__ void __launch_bounds__(256, 2)
out_gemm(const bf16_t* __restrict__ A, const bf16_t* __restrict__ W,
         const float* __restrict__ bias, float* __restrict__ out) {
  __shared__ bf16_t As[128 * 64];
  __shared__ bf16_t Bs[128 * 64];
  const int bid = blockIdx.x;
  const int lid = (bid & 7) * 32 + (bid >> 3);    // T1 swizzle (256 % 8 == 0)
  const int m0 = (lid >> 3) * 128, n0 = (lid & 7) * 128;
  gemm128_body<2>(A, W, bias, out, m0, n0, As, Bs);
}

// ---------------- fused dual flash attention (R10: 32x32 + in-reg P) -------
// S^T = mfma_32x32x16(A=K, B=Q): lane l holds S[kv = kvh*32+(m&3)+8*(m>>2)
// +4*(l>>5)][q = l&31]. Softmax: 31 local fmax + 1 shfl_xor(32). P -> PV
// B-fragments fully in-register: 16 cvt_pk + 8 permlane32_swap per branch.
// PV: O^T = mfma_32x32x16(A=V^T, B=P), d in 2 halves of 32.
__device__ __forceinline__ void attn_branch(
    const bf16_t* __restrict__ Kt, const bf16_t* __restrict__ Vt,
    const bf16x8 (&qB)[4], const int4 (&mk)[2][4],
    float& m_s, float& l_s, f32x16& oA, f32x16& oB, int lane31, int hh, int srow) {
  // ---- QK^T: 2 kv-halves x 4 k-steps ----
  f32x16 s[2];
#pragma unroll
  for (int kvh = 0; kvh < 2; ++kvh) {
    f32x16 a = z16();
    const bf16_t* kr = &Kt[(kvh * 32 + lane31) * 64];
#pragma unroll
    for (int kk = 0; kk < 4; ++kk) {
      const bf16x8 ka = *(const bf16x8*)&kr[(kk * 16 + hh * 8) ^ srow];
      a = __builtin_amdgcn_mfma_f32_32x32x16_bf16(ka, qB[kk], a, 0, 0, 0);
    }
    s[kvh] = a;
  }

  // ---- mask + scale (exp2 domain) + row max (lane-local + 1 swap) ----
  float tm = NEG_INF;
#pragma unroll
  for (int kvh = 0; kvh < 2; ++kvh)
#pragma unroll
    for (int m = 0; m < 16; ++m) {
      const int4 q4 = mk[kvh][m >> 2];
      const int mval = ((m & 3) == 0) ? q4.x : ((m & 3) == 1) ? q4.y
                     : ((m & 3) == 2) ? q4.z : q4.w;
      const float v = mval ? s[kvh][m] * K2E : NEG_INF;
      s[kvh][m] = v;
      tm = fmaxf(tm, v);
    }
  tm = fmaxf(tm, __shfl_xor(tm, 32));   // partner lane holds other 32 kv rows

  const float mnew = fmaxf(m_s, tm);
  const float sf = __builtin_amdgcn_exp2f(m_s - mnew);
  m_s = mnew;

  float pf = 0.f;
#pragma unroll
  for (int kvh = 0; kvh < 2; ++kvh)
#pragma unroll
    for (int m = 0; m < 16; ++m) {
      const float p = __builtin_amdgcn_exp2f(s[kvh][m] - mnew);
      s[kvh][m] = p;
      pf += p;
    }
  l_s = l_s * sf + pf;   // per-lane partial; final reduce via shfl_xor(32)
#pragma unroll
  for (int m = 0; m < 16; ++m) { oA[m] *= sf; oB[m] *= sf; }

  // ---- P -> PV B-fragments in registers (cvt_pk + permlane32_swap) ----
  bf16x8 pb[4];
#pragma unroll
  for (int kvh = 0; kvh < 2; ++kvh) {
    uint32_t pkA0 = cvtpk_bf16(s[kvh][0],  s[kvh][1]);
    uint32_t pkA1 = cvtpk_bf16(s[kvh][4],  s[kvh][5]);
    uint32_t pkB0 = cvtpk_bf16(s[kvh][2],  s[kvh][3]);
    uint32_t pkB1 = cvtpk_bf16(s[kvh][6],  s[kvh][7]);
    uint32_t pkA2 = cvtpk_bf16(s[kvh][8],  s[kvh][9]);
    uint32_t pkA3 = cvtpk_bf16(s[kvh][12], s[kvh][13]);
    uint32_t pkB2 = cvtpk_bf16(s[kvh][10], s[kvh][11]);
    uint32_t pkB3 = cvtpk_bf16(s[kvh][14], s[kvh][15]);
    plane32_swap(pkA0, pkA1);   // -> dwords 0,2 of PV step 2*kvh
    plane32_swap(pkB0, pkB1);   // -> dwords 1,3
    plane32_swap(pkA2, pkA3);   // -> dwords 0,2 of PV step 2*kvh+1
    plane32_swap(pkB2, pkB3);   // -> dwords 1,3
    const u32x4 w0 = {pkA0, pkB0, pkA1, pkB1};
    const u32x4 w1 = {pkA2, pkB2, pkA3, pkB3};
    pb[2 * kvh]     = __builtin_bit_cast(bf16x8, w0);
    pb[2 * kvh + 1] = __builtin_bit_cast(bf16x8, w1);
  }

  // ---- O^T += V^T @ P : 2 d-halves x 4 k-steps ----
#pragma unroll
  for (int s4 = 0; s4 < 4; ++s4) {
    const int col = (s4 * 16 + hh * 8) ^ srow;
    const bf16x8 va = *(const bf16x8*)&Vt[(lane31) * 64 + col];
    oA = __builtin_amdgcn_mfma_f32_32x32x16_bf16(va, pb[s4], oA, 0, 0, 0);
    const bf16x8 vb = *(const bf16x8*)&Vt[(32 + lane31) * 64 + col];
    oB = __builtin_amdgcn_mfma_f32_32x32x16_bf16(vb, pb[s4], oB, 0, 0, 0);
  }
}

__global__ void __launch_bounds__(256, 2)
attn_kernel(const bf16_t* __restrict__ q, const bf16_t* __restrict__ k,
            const bf16_t* __restrict__ rk, const bf16_t* __restrict__ vT,
            const bf16_t* __restrict__ rvT, const int* __restrict__ mask,
            bf16_t* __restrict__ x) {
  __shared__ bf16_t Ks[64 * 64], RKs[64 * 64], Vs[64 * 64], RVs[64 * 64]; // 32KB

  const int tid = threadIdx.x;
  const int lane = tid & 63;
  const int w = tid >> 6;
  const int lane31 = lane & 31, hh = lane >> 5;
  const int srow = (lane31 & 7) << 3;            // read-side XOR (row = ..+lane31)
  const int bid = blockIdx.x;
  const int lid = (bid & 7) * 64 + (bid >> 3);   // T1 swizzle (512 % 8 == 0)
  const int qt = lid & 7;
  const int bh = lid >> 3;
  const int b = bh >> 4, h = bh & 15;
  const int q0 = qt * 128;

  const bf16_t* qp = q + (size_t)bh * SEQ * DKH;
  const bf16_t* kp = k + (size_t)bh * SEQ * DKH;
  const bf16_t* rkp = rk + (size_t)bh * SEQ * DKH;
  const bf16_t* vp = vT + (size_t)bh * DKH * SEQ;
  const bf16_t* rvp = rvT + (size_t)bh * DKH * SEQ;
  const int* mp = mask + b * SEQ;
  const int lrow = lane >> 3;
  const int lcol = ((lane & 7) * 8) ^ ((lane >> 3) << 3);  // pre-swizzled source col

  // Q fragments (B-operand): wave owns 32 q-rows, one per lane31
  bf16x8 qB[4];
#pragma unroll
  for (int kk = 0; kk < 4; ++kk)
    qB[kk] = *(const bf16x8*)(qp + (size_t)(q0 + w * 32 + lane31) * DKH + kk * 16 + hh * 8);

  f32x16 ov[2] = {z16(), z16()}, orr[2] = {z16(), z16()};
  float mv = NEG_INF, mr = NEG_INF, lv = 0.f, lr = 0.f;

  for (int t = 0; t < 16; ++t) {
    const int kv0 = t * 64;
    if (t) __syncthreads();   // previous compute done before overwriting tiles
#pragma unroll
    for (int p = 0; p < 2; ++p) {
      const int row = w * 16 + p * 8;
      gload_lds16(kp  + (size_t)(kv0 + row + lrow) * DKH + lcol, &Ks[row * 64]);
      gload_lds16(rkp + (size_t)(kv0 + row + lrow) * DKH + lcol, &RKs[row * 64]);
      gload_lds16(vp  + (size_t)(row + lrow) * SEQ + kv0 + lcol, &Vs[row * 64]);
      gload_lds16(rvp + (size_t)(row + lrow) * SEQ + kv0 + lcol, &RVs[row * 64]);
    }
    __syncthreads();          // tiles ready

    // mask int4 per (kv-half, reg-group): rows kh*32 + 8*m' + 4*hh + 0..3
    int4 mk[2][4];
#pragma unroll
    for (int kh = 0; kh < 2; ++kh)
#pragma unroll
      for (int mq = 0; mq < 4; ++mq)
        mk[kh][mq] = *(const int4*)&mp[kv0 + kh * 32 + 8 * mq + 4 * hh];

    attn_branch(Ks,  Vs,  qB, mk, mv, lv, ov[0],  ov[1],  lane31, hh, srow);
    attn_branch(RKs, RVs, qB, mk, mr, lr, orr[0], orr[1], lane31, hh, srow);
  }

  // denominators: lanes l and l^32 hold complementary kv partial sums
  lv += __shfl_xor(lv, 32);
  lr += __shfl_xor(lr, 32);
  const float rlv = 1.0f / lv, rlr = 1.0f / lr;

  bf16_t* xb = x + (size_t)b * SEQ * DMODEL + (size_t)h * DKH;
  const int qrow = q0 + w * 32 + lane31;
#pragma unroll
  for (int dh = 0; dh < 2; ++dh)
#pragma unroll
    for (int mq = 0; mq < 4; ++mq) {
      bf16x4v pk;
#pragma unroll
      for (int r = 0; r < 4; ++r)
        pk[r] = (bf16_t)(ov[dh][4 * mq + r] * rlv + orr[dh][4 * mq + r] * rlr);
      *(bf16x4v*)&xb[(size_t)qrow * DMODEL + dh * 32 + 8 * mq + 4 * hh] = pk;
    }
}

// ---------------- host launch ---------------------------------------------
extern "C" void kernel_launch(void* const* d_in, const int* in_sizes, int n_in,
                              void* d_out, int out_size, void* d_ws, size_t ws_size,
                              hipStream_t stream) {
  (void)in_sizes; (void)n_in; (void)out_size; (void)ws_size;
  const float* query = (const float*)d_in[0];
  const float* key_  = (const float*)d_in[1];
  const float* value = (const float*)d_in[2];
  const float* weak  = (const float*)d_in[3];
  const int*   mask  = (const int*)d_in[4];
  const float* Wq  = (const float*)d_in[5];  const float* bq  = (const float*)d_in[6];
  const float* Wk  = (const float*)d_in[7];  const float* bk  = (const float*)d_in[8];
  const float* Wv  = (const float*)d_in[9];  const float* bv  = (const float*)d_in[10];
  const float* Wrk = (const float*)d_in[11]; const float* brk = (const float*)d_in[12];
  const float* Wrv = (const float*)d_in[13]; const float* brv = (const float*)d_in[14];
  const float* Wo  = (const float*)d_in[15]; const float* bo  = (const float*)d_in[16];

  char* ws = (char*)d_ws;
  size_t off = 0;
  auto alloc = [&](size_t bytes) {
    void* p = ws + off;
    off += (bytes + 255) & ~(size_t)255;
    return p;
  };
  const size_t SZ_X = NXE * sizeof(bf16_t); // 8 MB (256-aligned -> contiguous)
  const size_t SZ_W = NWE * sizeof(bf16_t); // 2 MB

  // X segments contiguous (q,k,v,r), W segments contiguous (q,k,v,rk,rv,o),
  // proj outputs contiguous (qh,kh,rkh,vTh,rvTh) -- proj_gemm indexes by base.
  bf16_t* Xq = (bf16_t*)alloc(SZ_X);
  bf16_t* Xk = (bf16_t*)alloc(SZ_X);
  bf16_t* Xv = (bf16_t*)alloc(SZ_X);
  bf16_t* Xr = (bf16_t*)alloc(SZ_X);
  bf16_t* Wqb  = (bf16_t*)alloc(SZ_W);
  bf16_t* Wkb  = (bf16_t*)alloc(SZ_W);
  bf16_t* Wvb  = (bf16_t*)alloc(SZ_W);
  bf16_t* Wrkb = (bf16_t*)alloc(SZ_W);
  bf16_t* Wrvb = (bf16_t*)alloc(SZ_W);
  bf16_t* Wob  = (bf16_t*)alloc(SZ_W);
  bf16_t* qh   = (bf16_t*)alloc(SZ_X);
  bf16_t* kh   = (bf16_t*)alloc(SZ_X);
  bf16_t* rkh  = (bf16_t*)alloc(SZ_X);
  bf16_t* vTh  = (bf16_t*)alloc(SZ_X);
  bf16_t* rvTh = (bf16_t*)alloc(SZ_X);
  bf16_t* xh   = (bf16_t*)alloc(SZ_X);
  (void)Xk; (void)Xv; (void)Xr; (void)Wkb; (void)Wvb; (void)Wrkb; (void)Wrvb;
  (void)kh; (void)rkh; (void)vTh; (void)rvTh;

  // f32 -> bf16
  cvt_multi<<<dim3(4096, 4), 256, 0, stream>>>(query, key_, value, weak, nullptr, nullptr,
                                               Xq, Xk, Xv, Xr, nullptr, nullptr,
                                               NB * SEQ * DMODEL);
  cvt_multi<<<dim3(1024, 6), 256, 0, stream>>>(Wq, Wk, Wv, Wrk, Wrv, Wo,
                                               Wqb, Wkb, Wvb, Wrkb, Wrvb, Wob,
                                               DMODEL * DMODEL);

  // all 5 projections in one grouped dispatch (1280 blocks, 128x128 tiles)
  proj_gemm<<<dim3(1280), 256, 0, stream>>>(Xq, Wqb, qh, bq, bk, bv, brk, brv);

  // fused dual attention: 512 blocks (q-tile 128, 32 q-rows/wave)
  attn_kernel<<<dim3(512), 256, 0, stream>>>(qh, kh, rkh, vTh, rvTh, mask, xh);

  // output projection -> f32 d_out (256 blocks, 128x128 tiles)
  out_gemm<<<dim3(256), 256, 0, stream>>>(xh, Wob, bo, (float*)d_out);
}

// Round 11
// 166.101 us; speedup vs baseline: 1.0775x; 1.0775x over previous
//
#include <hip/hip_runtime.h>
#include <stdint.h>

#define NB 4
#define NH 16
#define DKH 64
#define DMODEL 1024
#define SEQ 1024
#define SCALE 0.125f
#define NEG_INF -1.0e9f
#define K2E 0.18033688011112042f  // SCALE * log2(e): softmax in exp2 domain

typedef __bf16 bf16_t;
typedef __bf16 bf16x8 __attribute__((ext_vector_type(8)));
typedef __bf16 bf16x4v __attribute__((ext_vector_type(4)));
typedef float f32x4 __attribute__((ext_vector_type(4)));

typedef const uint32_t __attribute__((address_space(1)))* gas_ptr;
typedef uint32_t __attribute__((address_space(3)))* las_ptr;

// async global->LDS, 16B per lane, dest = wave-uniform base + lane*16
__device__ __forceinline__ void gload_lds16(const void* g, void* l) {
  __builtin_amdgcn_global_load_lds((gas_ptr)g, (las_ptr)l, 16, 0, 0);
}

// T2 XOR swizzle for [R][64] bf16 tiles: element col ^= (row&7)<<3; staging
// keeps LDS dest linear and pre-swizzles the GLOBAL source column.
// Journal: R2 swizzle: conflicts 1.99e7->0. R4 (256,4)->spill; (256,2) sane.
// R6 vis/rel reg-interleave HURT. R7 32q/wave shared frags: 77.9us (BEST).
// R8 branch-split, R9 2-phase/dbuf, R10 32x32+in-reg-P: all regressed ->
// reverted. R11 = R7 + R9's proven VALU wins only (mask-bias LDS table,
// defer-max THR=8). Do not touch the R7 barrier structure or MFMA shape.

// ---------------- f32 -> bf16 conversion (select tensor by blockIdx.y) ----
__global__ void cvt_multi(const float* __restrict__ i0, const float* __restrict__ i1,
                          const float* __restrict__ i2, const float* __restrict__ i3,
                          const float* __restrict__ i4, const float* __restrict__ i5,
                          bf16_t* o0, bf16_t* o1, bf16_t* o2, bf16_t* o3, bf16_t* o4, bf16_t* o5,
                          int n) {
  const int t = blockIdx.y;
  const float* in = (t == 0) ? i0 : (t == 1) ? i1 : (t == 2) ? i2 : (t == 3) ? i3 : (t == 4) ? i4 : i5;
  bf16_t* out = (t == 0) ? o0 : (t == 1) ? o1 : (t == 2) ? o2 : (t == 3) ? o3 : (t == 4) ? o4 : o5;
  const int idx = (blockIdx.x * 256 + threadIdx.x) * 4;
  if (idx >= n) return;
  const float4 v = *(const float4*)(in + idx);
  bf16x4v p;
  p[0] = (bf16_t)v.x; p[1] = (bf16_t)v.y; p[2] = (bf16_t)v.z; p[3] = (bf16_t)v.w;
  *(bf16x4v*)(out + idx) = p;
}

// ---------------- 128x128-tile GEMM core (m97 structure) -------------------
#define NXE ((size_t)NB * SEQ * DMODEL)      // elements per X/out segment
#define NWE ((size_t)DMODEL * DMODEL)

template<int MODE>
__device__ __forceinline__ void gemm128_body(
    const bf16_t* __restrict__ A, const bf16_t* __restrict__ W,
    const float* __restrict__ bias, void* __restrict__ outp,
    int m0, int n0, bf16_t* As, bf16_t* Bs) {
  const int tid = threadIdx.x;
  const int lane = tid & 63;
  const int w = tid >> 6;
  const int wm = w >> 1, wn = w & 1;
  const int g = lane >> 4, c = lane & 15;
  const int lrow = lane >> 3;
  const int lcol = ((lane & 7) * 8) ^ ((lane >> 3) << 3);  // pre-swizzled source col
  const int sc = (c & 7) << 3;                             // read-side XOR

  f32x4 acc[4][4] = {};

  for (int kt = 0; kt < DMODEL; kt += 64) {
#pragma unroll
    for (int p = 0; p < 4; ++p) {
      const int row = w * 32 + p * 8;
      gload_lds16(A + (size_t)(m0 + row + lrow) * DMODEL + kt + lcol, &As[row * 64]);
      gload_lds16(W + (size_t)(n0 + row + lrow) * DMODEL + kt + lcol, &Bs[row * 64]);
    }
    __syncthreads();
    bf16x8 af[4][2], bfr[4][2];
#pragma unroll
    for (int i = 0; i < 4; ++i)
#pragma unroll
      for (int kk = 0; kk < 2; ++kk) {
        af[i][kk]  = *(const bf16x8*)&As[(wm * 64 + i * 16 + c) * 64 + ((kk * 32 + g * 8) ^ sc)];
        bfr[i][kk] = *(const bf16x8*)&Bs[(wn * 64 + i * 16 + c) * 64 + ((kk * 32 + g * 8) ^ sc)];
      }
#pragma unroll
    for (int i = 0; i < 4; ++i)
#pragma unroll
      for (int j = 0; j < 4; ++j) {
        acc[i][j] = __builtin_amdgcn_mfma_f32_16x16x32_bf16(af[i][0], bfr[j][0], acc[i][j], 0, 0, 0);
        acc[i][j] = __builtin_amdgcn_mfma_f32_16x16x32_bf16(af[i][1], bfr[j][1], acc[i][j], 0, 0, 0);
      }
    __syncthreads();
  }

  float bv4[4];
#pragma unroll
  for (int j = 0; j < 4; ++j) bv4[j] = bias[n0 + wn * 64 + j * 16 + c];

#pragma unroll
  for (int i = 0; i < 4; ++i) {
    const int mrow = m0 + wm * 64 + i * 16 + g * 4;   // C-layout: row = g*4 + r
    const int b_ = mrow >> 10, l_ = mrow & 1023;
#pragma unroll
    for (int j = 0; j < 4; ++j) {
      const int n = n0 + wn * 64 + j * 16 + c;        // C-layout: col = lane&15
      if (MODE == 2) {
        float* o = (float*)outp;
#pragma unroll
        for (int r = 0; r < 4; ++r)
          o[(size_t)(mrow + r) * DMODEL + n] = acc[i][j][r] + bv4[j];
      } else if (MODE == 0) {
        bf16_t* o = (bf16_t*)outp;
        const int h_ = n >> 6, dk_ = n & 63;
#pragma unroll
        for (int r = 0; r < 4; ++r)
          o[((size_t)(b_ * NH + h_) * SEQ + l_ + r) * DKH + dk_] =
              (bf16_t)(acc[i][j][r] + bv4[j]);
      } else { // MODE 1: transposed [B,H,DK,L]; 4 consecutive l -> packed 8B store
        bf16_t* o = (bf16_t*)outp;
        const int h_ = n >> 6, dk_ = n & 63;
        bf16x4v pk;
#pragma unroll
        for (int r = 0; r < 4; ++r) pk[r] = (bf16_t)(acc[i][j][r] + bv4[j]);
        *(bf16x4v*)&o[((size_t)(b_ * NH + h_) * DKH + dk_) * SEQ + l_] = pk;
      }
    }
  }
}

// grouped projection: 5 segments x (32 m-tiles x 8 n-tiles) = 1280 blocks
__global__ void __launch_bounds__(256, 2)
proj_gemm(const bf16_t* __restrict__ Xbase, const bf16_t* __restrict__ Wbase,
          bf16_t* __restrict__ Obase,
          const float* __restrict__ b0, const float* __restrict__ b1,
          const float* __restrict__ b2, const float* __restrict__ b3,
          const float* __restrict__ b4) {
  __shared__ bf16_t As[128 * 64];
  __shared__ bf16_t Bs[128 * 64];
  const int bid = blockIdx.x;
  const int lid = (bid & 7) * 160 + (bid >> 3);   // T1 swizzle (1280 % 8 == 0)
  const int seg = lid >> 8;                       // 0..4
  const int rr = lid & 255;
  const int m0 = (rr >> 3) * 128, n0 = (rr & 7) * 128;

  const bf16_t* A = Xbase + (size_t)((seg < 3) ? seg : 3) * NXE;
  const bf16_t* W = Wbase + (size_t)seg * NWE;
  const int ooff = (seg == 0) ? 0 : (seg == 1) ? 1 : (seg == 2) ? 3 : (seg == 3) ? 2 : 4;
  bf16_t* out = Obase + (size_t)ooff * NXE;
  const float* bias = (seg == 0) ? b0 : (seg == 1) ? b1 : (seg == 2) ? b2 : (seg == 3) ? b3 : b4;

  if (seg == 2 || seg == 4) gemm128_body<1>(A, W, bias, out, m0, n0, As, Bs);
  else                      gemm128_body<0>(A, W, bias, out, m0, n0, As, Bs);
}

// output projection -> f32 d_out: 32 x 8 = 256 blocks
__global__ void __launch_bounds__(256, 2)
out_gemm(const bf16_t* __restrict__ A, const bf16_t* __restrict__ W,
         const float* __restrict__ bias, float* __restrict__ out) {
  __shared__ bf16_t As[128 * 64];
  __shared__ bf16_t Bs[128 * 64];
  const int bid = blockIdx.x;
  const int lid = (bid & 7) * 32 + (bid >> 3);    // T1 swizzle (256 % 8 == 0)
  const int m0 = (lid >> 3) * 128, n0 = (lid & 7) * 128;
  gemm128_body<2>(A, W, bias, out, m0, n0, As, Bs);
}

// ---------------- fused dual flash attention (R7 + VALU diet) --------------
// S^T = mfma(A=K, B=Q): lane (g,c) holds S[kv=f*16+g*4+r][q=c]. Wave owns 32
// q-rows as TWO 16-col Q fragments sharing one K/V fragment read. Mask is an
// additive f32 bias table in LDS (built once); defer-max THR=8 skips the
// rescale chain when the running max grows by <8 (exact in relative terms).
__device__ __forceinline__ void attn_step(
    const bf16_t* __restrict__ Kt, const bf16_t* __restrict__ Vt,
    bf16_t* __restrict__ Pw, const bf16x8 (&qf)[2][2], const f32x4 (&mb)[4],
    float (&m_s)[2], float (&l_s)[2], f32x4 (&o_s)[2][4], int lane) {
  const int g = lane >> 4, c = lane & 15;
  const int sc = (c & 7) << 3;

  f32x4 s[2][4];
  {
    bf16x8 kfr[4][2];
#pragma unroll
    for (int f = 0; f < 4; ++f) {
      kfr[f][0] = *(const bf16x8*)&Kt[(f * 16 + c) * 64 + ((g * 8) ^ sc)];
      kfr[f][1] = *(const bf16x8*)&Kt[(f * 16 + c) * 64 + ((32 + g * 8) ^ sc)];
    }
#pragma unroll
    for (int i = 0; i < 2; ++i)
#pragma unroll
      for (int f = 0; f < 4; ++f) {
        f32x4 a = {0.f, 0.f, 0.f, 0.f};
        a = __builtin_amdgcn_mfma_f32_16x16x32_bf16(kfr[f][0], qf[i][0], a, 0, 0, 0);
        a = __builtin_amdgcn_mfma_f32_16x16x32_bf16(kfr[f][1], qf[i][1], a, 0, 0, 0);
        s[i][f] = a;
      }
  } // kfr dead -> caps register peak

  // scale into exp2 domain + additive mask bias (fused fma; masked -> -1e9)
#pragma unroll
  for (int i = 0; i < 2; ++i)
#pragma unroll
    for (int f = 0; f < 4; ++f)
#pragma unroll
      for (int r = 0; r < 4; ++r)
        s[i][f][r] = s[i][f][r] * K2E + mb[f][r];

  // per-half online softmax with defer-max
#pragma unroll
  for (int i = 0; i < 2; ++i) {
    float tm = fmaxf(fmaxf(s[i][0][0], s[i][0][1]), fmaxf(s[i][0][2], s[i][0][3]));
#pragma unroll
    for (int f = 1; f < 4; ++f)
      tm = fmaxf(tm, fmaxf(fmaxf(s[i][f][0], s[i][f][1]), fmaxf(s[i][f][2], s[i][f][3])));
    tm = fmaxf(tm, __shfl_xor(tm, 16));
    tm = fmaxf(tm, __shfl_xor(tm, 32));
    if (!__all(tm <= m_s[i] + 8.0f)) {   // rare: rescale only on real max growth
      const float mnew = fmaxf(m_s[i], tm);
      const float sf = __builtin_amdgcn_exp2f(m_s[i] - mnew);
      m_s[i] = mnew;
      l_s[i] *= sf;
#pragma unroll
      for (int jd = 0; jd < 4; ++jd)
#pragma unroll
        for (int r = 0; r < 4; ++r) o_s[i][jd][r] *= sf;
    }
    float pf = 0.f;
#pragma unroll
    for (int f = 0; f < 4; ++f) {
      bf16x4v pk;
#pragma unroll
      for (int r = 0; r < 4; ++r) {
        const float p = __builtin_amdgcn_exp2f(s[i][f][r] - m_s[i]);
        pf += p;
        pk[r] = (bf16_t)p;
      }
      *(bf16x4v*)&Pw[i * 1024 + c * 64 + ((f * 16 + g * 4) ^ sc)] = pk;
    }
    l_s[i] += pf;
  }

  // O^T += V^T @ P : V fragment reads SHARED across both q-halves
  bf16x8 pa[2][2];
#pragma unroll
  for (int i = 0; i < 2; ++i) {
    pa[i][0] = *(const bf16x8*)&Pw[i * 1024 + c * 64 + ((g * 8) ^ sc)];
    pa[i][1] = *(const bf16x8*)&Pw[i * 1024 + c * 64 + ((32 + g * 8) ^ sc)];
  }
#pragma unroll
  for (int jd = 0; jd < 4; ++jd) {
    const bf16x8 v0 = *(const bf16x8*)&Vt[(jd * 16 + c) * 64 + ((g * 8) ^ sc)];
    const bf16x8 v1 = *(const bf16x8*)&Vt[(jd * 16 + c) * 64 + ((32 + g * 8) ^ sc)];
#pragma unroll
    for (int i = 0; i < 2; ++i) {
      o_s[i][jd] = __builtin_amdgcn_mfma_f32_16x16x32_bf16(v0, pa[i][0], o_s[i][jd], 0, 0, 0);
      o_s[i][jd] = __builtin_amdgcn_mfma_f32_16x16x32_bf16(v1, pa[i][1], o_s[i][jd], 0, 0, 0);
    }
  }
}

__global__ void __launch_bounds__(256, 2)
attn_kernel(const bf16_t* __restrict__ q, const bf16_t* __restrict__ k,
            const bf16_t* __restrict__ rk, const bf16_t* __restrict__ vT,
            const bf16_t* __restrict__ rvT, const int* __restrict__ mask,
            bf16_t* __restrict__ x) {
  __shared__ bf16_t Ks[64 * 64], RKs[64 * 64], Vs[64 * 64], RVs[64 * 64]; // 32KB
  __shared__ bf16_t Ps[4][2][16 * 64];                                   // 16KB
  __shared__ float Mb[SEQ];                                              // 4KB

  const int tid = threadIdx.x;
  const int lane = tid & 63;
  const int w = tid >> 6;
  const int g = lane >> 4, c = lane & 15;
  const int bid = blockIdx.x;
  const int lid = (bid & 7) * 64 + (bid >> 3);   // T1 swizzle (512 % 8 == 0)
  const int qt = lid & 7;
  const int bh = lid >> 3;
  const int b = bh >> 4, h = bh & 15;
  const int q0 = qt * 128;

  const bf16_t* qp = q + (size_t)bh * SEQ * DKH;
  const bf16_t* kp = k + (size_t)bh * SEQ * DKH;
  const bf16_t* rkp = rk + (size_t)bh * SEQ * DKH;
  const bf16_t* vp = vT + (size_t)bh * DKH * SEQ;
  const bf16_t* rvp = rvT + (size_t)bh * DKH * SEQ;
  const int* mp = mask + b * SEQ;
  const int lrow = lane >> 3;
  const int lcol = ((lane & 7) * 8) ^ ((lane >> 3) << 3);  // pre-swizzled source col

  // mask bias table (written pre-barrier; first in-loop barrier publishes it)
#pragma unroll
  for (int i = 0; i < 4; ++i) {
    const int idx = i * 256 + tid;
    Mb[idx] = (mp[idx] == 0) ? NEG_INF : 0.0f;
  }

  // Q fragments in registers: wave owns 32 q-rows as two 16-col B-fragments
  bf16x8 qf[2][2];
#pragma unroll
  for (int i = 0; i < 2; ++i)
#pragma unroll
    for (int kk = 0; kk < 2; ++kk)
      qf[i][kk] = *(const bf16x8*)(qp + (size_t)(q0 + w * 32 + i * 16 + c) * DKH + kk * 32 + g * 8);

  f32x4 ov[2][4] = {}, orl[2][4] = {};
  float mv[2] = {NEG_INF, NEG_INF}, mr[2] = {NEG_INF, NEG_INF};
  float lv[2] = {0.f, 0.f}, lr[2] = {0.f, 0.f};

  for (int t = 0; t < 16; ++t) {
    const int kv0 = t * 64;
    if (t) __syncthreads();   // previous compute done before overwriting tiles
#pragma unroll
    for (int p = 0; p < 2; ++p) {
      const int row = w * 16 + p * 8;
      gload_lds16(kp  + (size_t)(kv0 + row + lrow) * DKH + lcol, &Ks[row * 64]);
      gload_lds16(rkp + (size_t)(kv0 + row + lrow) * DKH + lcol, &RKs[row * 64]);
      gload_lds16(vp  + (size_t)(row + lrow) * SEQ + kv0 + lcol, &Vs[row * 64]);
      gload_lds16(rvp + (size_t)(row + lrow) * SEQ + kv0 + lcol, &RVs[row * 64]);
    }
    __syncthreads();          // tiles (and Mb, at t=0) ready

    f32x4 mb[4];
#pragma unroll
    for (int f = 0; f < 4; ++f)
      mb[f] = *(const f32x4*)&Mb[kv0 + f * 16 + g * 4];

    attn_step(Ks,  Vs,  &Ps[w][0][0], qf, mb, mv, lv, ov,  lane);
    attn_step(RKs, RVs, &Ps[w][0][0], qf, mb, mr, lr, orl, lane);
  }

  // denominators: reduce per-lane partials across the 4 g-groups
#pragma unroll
  for (int i = 0; i < 2; ++i) {
    lv[i] += __shfl_xor(lv[i], 16); lv[i] += __shfl_xor(lv[i], 32);
    lr[i] += __shfl_xor(lr[i], 16); lr[i] += __shfl_xor(lr[i], 32);
  }

  bf16_t* xb = x + (size_t)b * SEQ * DMODEL + (size_t)h * DKH;
#pragma unroll
  for (int i = 0; i < 2; ++i) {
    const float rlv = 1.0f / lv[i], rlr = 1.0f / lr[i];
    const int qrow = q0 + w * 32 + i * 16 + c;
#pragma unroll
    for (int jd = 0; jd < 4; ++jd) {
      bf16x4v pk;
#pragma unroll
      for (int r = 0; r < 4; ++r)
        pk[r] = (bf16_t)(ov[i][jd][r] * rlv + orl[i][jd][r] * rlr);
      *(bf16x4v*)&xb[(size_t)qrow * DMODEL + jd * 16 + g * 4] = pk;
    }
  }
}

// ---------------- host launch ---------------------------------------------
extern "C" void kernel_launch(void* const* d_in, const int* in_sizes, int n_in,
                              void* d_out, int out_size, void* d_ws, size_t ws_size,
                              hipStream_t stream) {
  (void)in_sizes; (void)n_in; (void)out_size; (void)ws_size;
  const float* query = (const float*)d_in[0];
  const float* key_  = (const float*)d_in[1];
  const float* value = (const float*)d_in[2];
  const float* weak  = (const float*)d_in[3];
  const int*   mask  = (const int*)d_in[4];
  const float* Wq  = (const float*)d_in[5];  const float* bq  = (const float*)d_in[6];
  const float* Wk  = (const float*)d_in[7];  const float* bk  = (const float*)d_in[8];
  const float* Wv  = (const float*)d_in[9];  const float* bv  = (const float*)d_in[10];
  const float* Wrk = (const float*)d_in[11]; const float* brk = (const float*)d_in[12];
  const float* Wrv = (const float*)d_in[13]; const float* brv = (const float*)d_in[14];
  const float* Wo  = (const float*)d_in[15]; const float* bo  = (const float*)d_in[16];

  char* ws = (char*)d_ws;
  size_t off = 0;
  auto alloc = [&](size_t bytes) {
    void* p = ws + off;
    off += (bytes + 255) & ~(size_t)255;
    return p;
  };
  const size_t SZ_X = NXE * sizeof(bf16_t); // 8 MB (256-aligned -> contiguous)
  const size_t SZ_W = NWE * sizeof(bf16_t); // 2 MB

  // X segments contiguous (q,k,v,r), W segments contiguous (q,k,v,rk,rv,o),
  // proj outputs contiguous (qh,kh,rkh,vTh,rvTh) -- proj_gemm indexes by base.
  bf16_t* Xq = (bf16_t*)alloc(SZ_X);
  bf16_t* Xk = (bf16_t*)alloc(SZ_X);
  bf16_t* Xv = (bf16_t*)alloc(SZ_X);
  bf16_t* Xr = (bf16_t*)alloc(SZ_X);
  bf16_t* Wqb  = (bf16_t*)alloc(SZ_W);
  bf16_t* Wkb  = (bf16_t*)alloc(SZ_W);
  bf16_t* Wvb  = (bf16_t*)alloc(SZ_W);
  bf16_t* Wrkb = (bf16_t*)alloc(SZ_W);
  bf16_t* Wrvb = (bf16_t*)alloc(SZ_W);
  bf16_t* Wob  = (bf16_t*)alloc(SZ_W);
  bf16_t* qh   = (bf16_t*)alloc(SZ_X);
  bf16_t* kh   = (bf16_t*)alloc(SZ_X);
  bf16_t* rkh  = (bf16_t*)alloc(SZ_X);
  bf16_t* vTh  = (bf16_t*)alloc(SZ_X);
  bf16_t* rvTh = (bf16_t*)alloc(SZ_X);
  bf16_t* xh   = (bf16_t*)alloc(SZ_X);
  (void)Xk; (void)Xv; (void)Xr; (void)Wkb; (void)Wvb; (void)Wrkb; (void)Wrvb;
  (void)kh; (void)rkh; (void)vTh; (void)rvTh;

  // f32 -> bf16
  cvt_multi<<<dim3(4096, 4), 256, 0, stream>>>(query, key_, value, weak, nullptr, nullptr,
                                               Xq, Xk, Xv, Xr, nullptr, nullptr,
                                               NB * SEQ * DMODEL);
  cvt_multi<<<dim3(1024, 6), 256, 0, stream>>>(Wq, Wk, Wv, Wrk, Wrv, Wo,
                                               Wqb, Wkb, Wvb, Wrkb, Wrvb, Wob,
                                               DMODEL * DMODEL);

  // all 5 projections in one grouped dispatch (1280 blocks, 128x128 tiles)
  proj_gemm<<<dim3(1280), 256, 0, stream>>>(Xq, Wqb, qh, bq, bk, bv, brk, brv);

  // fused dual attention: 512 blocks (q-tile 128, 32 q-rows/wave)
  attn_kernel<<<dim3(512), 256, 0, stream>>>(qh, kh, rkh, vTh, rvTh, mask, xh);

  // output projection -> f32 d_out (256 blocks, 128x128 tiles)
  out_gemm<<<dim3(256), 256, 0, stream>>>(xh, Wob, bo, (float*)d_out);
}

// Round 12
// 164.974 us; speedup vs baseline: 1.0848x; 1.0068x over previous
//
#include <hip/hip_runtime.h>
#include <stdint.h>

#define NB 4
#define NH 16
#define DKH 64
#define DMODEL 1024
#define SEQ 1024
#define SCALE 0.125f
#define NEG_INF -1.0e9f
#define K2E 0.18033688011112042f  // SCALE * log2(e): softmax in exp2 domain

typedef __bf16 bf16_t;
typedef __bf16 bf16x8 __attribute__((ext_vector_type(8)));
typedef __bf16 bf16x4v __attribute__((ext_vector_type(4)));
typedef float f32x4 __attribute__((ext_vector_type(4)));

typedef const uint32_t __attribute__((address_space(1)))* gas_ptr;
typedef uint32_t __attribute__((address_space(3)))* las_ptr;

// async global->LDS, 16B per lane, dest = wave-uniform base + lane*16
__device__ __forceinline__ void gload_lds16(const void* g, void* l) {
  __builtin_amdgcn_global_load_lds((gas_ptr)g, (las_ptr)l, 16, 0, 0);
}

// T2 XOR swizzle for [R][64] bf16 tiles: element col ^= (row&7)<<3; staging
// keeps LDS dest linear and pre-swizzles the GLOBAL source column.
// Journal: R2 swizzle: conflicts 1.99e7->0. R4 (256,4)->spill; (256,2) sane.
// R6 vis/rel reg-interleave HURT (S doubled). R7 32q/wave shared frags: 77.9.
// R8 split / R9 2-phase / R10 32x32: regressed -> reverted. R11 = R7 + mask
// bias table + defer-max: 76.7us. P-store "conflicts" (4.0/store) are the
// structural b64 floor -- not fixable, don't chase. R12: separate Pv/Pr
// buffers + step reorder (QKv SMv | QKr SMr | PVv PVr) + setprio on PV.

// ---------------- f32 -> bf16 conversion (select tensor by blockIdx.y) ----
__global__ void cvt_multi(const float* __restrict__ i0, const float* __restrict__ i1,
                          const float* __restrict__ i2, const float* __restrict__ i3,
                          const float* __restrict__ i4, const float* __restrict__ i5,
                          bf16_t* o0, bf16_t* o1, bf16_t* o2, bf16_t* o3, bf16_t* o4, bf16_t* o5,
                          int n) {
  const int t = blockIdx.y;
  const float* in = (t == 0) ? i0 : (t == 1) ? i1 : (t == 2) ? i2 : (t == 3) ? i3 : (t == 4) ? i4 : i5;
  bf16_t* out = (t == 0) ? o0 : (t == 1) ? o1 : (t == 2) ? o2 : (t == 3) ? o3 : (t == 4) ? o4 : o5;
  const int idx = (blockIdx.x * 256 + threadIdx.x) * 4;
  if (idx >= n) return;
  const float4 v = *(const float4*)(in + idx);
  bf16x4v p;
  p[0] = (bf16_t)v.x; p[1] = (bf16_t)v.y; p[2] = (bf16_t)v.z; p[3] = (bf16_t)v.w;
  *(bf16x4v*)(out + idx) = p;
}

// ---------------- 128x128-tile GEMM core (m97 structure) -------------------
#define NXE ((size_t)NB * SEQ * DMODEL)      // elements per X/out segment
#define NWE ((size_t)DMODEL * DMODEL)

template<int MODE>
__device__ __forceinline__ void gemm128_body(
    const bf16_t* __restrict__ A, const bf16_t* __restrict__ W,
    const float* __restrict__ bias, void* __restrict__ outp,
    int m0, int n0, bf16_t* As, bf16_t* Bs) {
  const int tid = threadIdx.x;
  const int lane = tid & 63;
  const int w = tid >> 6;
  const int wm = w >> 1, wn = w & 1;
  const int g = lane >> 4, c = lane & 15;
  const int lrow = lane >> 3;
  const int lcol = ((lane & 7) * 8) ^ ((lane >> 3) << 3);  // pre-swizzled source col
  const int sc = (c & 7) << 3;                             // read-side XOR

  f32x4 acc[4][4] = {};

  for (int kt = 0; kt < DMODEL; kt += 64) {
#pragma unroll
    for (int p = 0; p < 4; ++p) {
      const int row = w * 32 + p * 8;
      gload_lds16(A + (size_t)(m0 + row + lrow) * DMODEL + kt + lcol, &As[row * 64]);
      gload_lds16(W + (size_t)(n0 + row + lrow) * DMODEL + kt + lcol, &Bs[row * 64]);
    }
    __syncthreads();
    bf16x8 af[4][2], bfr[4][2];
#pragma unroll
    for (int i = 0; i < 4; ++i)
#pragma unroll
      for (int kk = 0; kk < 2; ++kk) {
        af[i][kk]  = *(const bf16x8*)&As[(wm * 64 + i * 16 + c) * 64 + ((kk * 32 + g * 8) ^ sc)];
        bfr[i][kk] = *(const bf16x8*)&Bs[(wn * 64 + i * 16 + c) * 64 + ((kk * 32 + g * 8) ^ sc)];
      }
#pragma unroll
    for (int i = 0; i < 4; ++i)
#pragma unroll
      for (int j = 0; j < 4; ++j) {
        acc[i][j] = __builtin_amdgcn_mfma_f32_16x16x32_bf16(af[i][0], bfr[j][0], acc[i][j], 0, 0, 0);
        acc[i][j] = __builtin_amdgcn_mfma_f32_16x16x32_bf16(af[i][1], bfr[j][1], acc[i][j], 0, 0, 0);
      }
    __syncthreads();
  }

  float bv4[4];
#pragma unroll
  for (int j = 0; j < 4; ++j) bv4[j] = bias[n0 + wn * 64 + j * 16 + c];

#pragma unroll
  for (int i = 0; i < 4; ++i) {
    const int mrow = m0 + wm * 64 + i * 16 + g * 4;   // C-layout: row = g*4 + r
    const int b_ = mrow >> 10, l_ = mrow & 1023;
#pragma unroll
    for (int j = 0; j < 4; ++j) {
      const int n = n0 + wn * 64 + j * 16 + c;        // C-layout: col = lane&15
      if (MODE == 2) {
        float* o = (float*)outp;
#pragma unroll
        for (int r = 0; r < 4; ++r)
          o[(size_t)(mrow + r) * DMODEL + n] = acc[i][j][r] + bv4[j];
      } else if (MODE == 0) {
        bf16_t* o = (bf16_t*)outp;
        const int h_ = n >> 6, dk_ = n & 63;
#pragma unroll
        for (int r = 0; r < 4; ++r)
          o[((size_t)(b_ * NH + h_) * SEQ + l_ + r) * DKH + dk_] =
              (bf16_t)(acc[i][j][r] + bv4[j]);
      } else { // MODE 1: transposed [B,H,DK,L]; 4 consecutive l -> packed 8B store
        bf16_t* o = (bf16_t*)outp;
        const int h_ = n >> 6, dk_ = n & 63;
        bf16x4v pk;
#pragma unroll
        for (int r = 0; r < 4; ++r) pk[r] = (bf16_t)(acc[i][j][r] + bv4[j]);
        *(bf16x4v*)&o[((size_t)(b_ * NH + h_) * DKH + dk_) * SEQ + l_] = pk;
      }
    }
  }
}

// grouped projection: 5 segments x (32 m-tiles x 8 n-tiles) = 1280 blocks
__global__ void __launch_bounds__(256, 2)
proj_gemm(const bf16_t* __restrict__ Xbase, const bf16_t* __restrict__ Wbase,
          bf16_t* __restrict__ Obase,
          const float* __restrict__ b0, const float* __restrict__ b1,
          const float* __restrict__ b2, const float* __restrict__ b3,
          const float* __restrict__ b4) {
  __shared__ bf16_t As[128 * 64];
  __shared__ bf16_t Bs[128 * 64];
  const int bid = blockIdx.x;
  const int lid = (bid & 7) * 160 + (bid >> 3);   // T1 swizzle (1280 % 8 == 0)
  const int seg = lid >> 8;                       // 0..4
  const int rr = lid & 255;
  const int m0 = (rr >> 3) * 128, n0 = (rr & 7) * 128;

  const bf16_t* A = Xbase + (size_t)((seg < 3) ? seg : 3) * NXE;
  const bf16_t* W = Wbase + (size_t)seg * NWE;
  const int ooff = (seg == 0) ? 0 : (seg == 1) ? 1 : (seg == 2) ? 3 : (seg == 3) ? 2 : 4;
  bf16_t* out = Obase + (size_t)ooff * NXE;
  const float* bias = (seg == 0) ? b0 : (seg == 1) ? b1 : (seg == 2) ? b2 : (seg == 3) ? b3 : b4;

  if (seg == 2 || seg == 4) gemm128_body<1>(A, W, bias, out, m0, n0, As, Bs);
  else                      gemm128_body<0>(A, W, bias, out, m0, n0, As, Bs);
}

// output projection -> f32 d_out: 32 x 8 = 256 blocks
__global__ void __launch_bounds__(256, 2)
out_gemm(const bf16_t* __restrict__ A, const bf16_t* __restrict__ W,
         const float* __restrict__ bias, float* __restrict__ out) {
  __shared__ bf16_t As[128 * 64];
  __shared__ bf16_t Bs[128 * 64];
  const int bid = blockIdx.x;
  const int lid = (bid & 7) * 32 + (bid >> 3);    // T1 swizzle (256 % 8 == 0)
  const int m0 = (lid >> 3) * 128, n0 = (lid & 7) * 128;
  gemm128_body<2>(A, W, bias, out, m0, n0, As, Bs);
}

// ---------------- fused dual flash attention (R12) -------------------------
// R11 math, reordered step with per-branch P buffers:
//   QKv -> SMv -> Pv | QKr -> SMr -> Pr | setprio(1) PVv PVr setprio(0)
// Pv's write->read turnaround hidden under QKr+SMr; PV = 32 clustered MFMAs.
__global__ void __launch_bounds__(256, 2)
attn_kernel(const bf16_t* __restrict__ q, const bf16_t* __restrict__ k,
            const bf16_t* __restrict__ rk, const bf16_t* __restrict__ vT,
            const bf16_t* __restrict__ rvT, const int* __restrict__ mask,
            bf16_t* __restrict__ x) {
  extern __shared__ __align__(256) bf16_t smem[];
  bf16_t* Ks  = smem;                 // 8KB
  bf16_t* RKs = Ks  + 64 * 64;        // 8KB
  bf16_t* Vs  = RKs + 64 * 64;        // 8KB
  bf16_t* RVs = Vs  + 64 * 64;        // 8KB
  bf16_t* Pbase = RVs + 64 * 64;      // 4 waves x 2 branches x 2048 = 32KB
  float* Mb = (float*)(Pbase + 8 * 2048);  // 4KB -> total 68KB

  const int tid = threadIdx.x;
  const int lane = tid & 63;
  const int w = tid >> 6;
  const int g = lane >> 4, c = lane & 15;
  const int sc = (c & 7) << 3;
  const int bid = blockIdx.x;
  const int lid = (bid & 7) * 64 + (bid >> 3);   // T1 swizzle (512 % 8 == 0)
  const int qt = lid & 7;
  const int bh = lid >> 3;
  const int b = bh >> 4, h = bh & 15;
  const int q0 = qt * 128;

  const bf16_t* qp = q + (size_t)bh * SEQ * DKH;
  const bf16_t* kp = k + (size_t)bh * SEQ * DKH;
  const bf16_t* rkp = rk + (size_t)bh * SEQ * DKH;
  const bf16_t* vp = vT + (size_t)bh * DKH * SEQ;
  const bf16_t* rvp = rvT + (size_t)bh * DKH * SEQ;
  const int* mp = mask + b * SEQ;
  const int lrow = lane >> 3;
  const int lcol = ((lane & 7) * 8) ^ ((lane >> 3) << 3);  // pre-swizzled source col

  bf16_t* Pwv = Pbase + w * 2048;            // [2 halves][16 q][64 kv]
  bf16_t* Pwr = Pbase + (4 + w) * 2048;

  // mask bias table (published by the t=0 in-loop barrier)
#pragma unroll
  for (int i = 0; i < 4; ++i) {
    const int idx = i * 256 + tid;
    Mb[idx] = (mp[idx] == 0) ? NEG_INF : 0.0f;
  }

  // Q fragments in registers: wave owns 32 q-rows as two 16-col B-fragments
  bf16x8 qf[2][2];
#pragma unroll
  for (int i = 0; i < 2; ++i)
#pragma unroll
    for (int kk = 0; kk < 2; ++kk)
      qf[i][kk] = *(const bf16x8*)(qp + (size_t)(q0 + w * 32 + i * 16 + c) * DKH + kk * 32 + g * 8);

  f32x4 ov[2][4] = {}, orl[2][4] = {};
  float mv[2] = {NEG_INF, NEG_INF}, mr[2] = {NEG_INF, NEG_INF};
  float lv[2] = {0.f, 0.f}, lr[2] = {0.f, 0.f};

  // QK^T + online softmax + P write for one branch
  auto qk_sm = [&](const bf16_t* Kt, bf16_t* Pb, const f32x4 (&mb)[4],
                   float (&m_s)[2], float (&l_s)[2], f32x4 (&o_s)[2][4]) {
    f32x4 s[2][4];
    {
      bf16x8 kfr[4][2];
#pragma unroll
      for (int f = 0; f < 4; ++f) {
        kfr[f][0] = *(const bf16x8*)&Kt[(f * 16 + c) * 64 + ((g * 8) ^ sc)];
        kfr[f][1] = *(const bf16x8*)&Kt[(f * 16 + c) * 64 + ((32 + g * 8) ^ sc)];
      }
#pragma unroll
      for (int i = 0; i < 2; ++i)
#pragma unroll
        for (int f = 0; f < 4; ++f) {
          f32x4 a = {0.f, 0.f, 0.f, 0.f};
          a = __builtin_amdgcn_mfma_f32_16x16x32_bf16(kfr[f][0], qf[i][0], a, 0, 0, 0);
          a = __builtin_amdgcn_mfma_f32_16x16x32_bf16(kfr[f][1], qf[i][1], a, 0, 0, 0);
          s[i][f] = a;
        }
    } // kfr dead -> caps register peak

#pragma unroll
    for (int i = 0; i < 2; ++i)
#pragma unroll
      for (int f = 0; f < 4; ++f)
#pragma unroll
        for (int r = 0; r < 4; ++r)
          s[i][f][r] = s[i][f][r] * K2E + mb[f][r];

#pragma unroll
    for (int i = 0; i < 2; ++i) {
      float tm = fmaxf(fmaxf(s[i][0][0], s[i][0][1]), fmaxf(s[i][0][2], s[i][0][3]));
#pragma unroll
      for (int f = 1; f < 4; ++f)
        tm = fmaxf(tm, fmaxf(fmaxf(s[i][f][0], s[i][f][1]), fmaxf(s[i][f][2], s[i][f][3])));
      tm = fmaxf(tm, __shfl_xor(tm, 16));
      tm = fmaxf(tm, __shfl_xor(tm, 32));
      if (!__all(tm <= m_s[i] + 8.0f)) {   // defer-max: rescale only on real growth
        const float mnew = fmaxf(m_s[i], tm);
        const float sf = __builtin_amdgcn_exp2f(m_s[i] - mnew);
        m_s[i] = mnew;
        l_s[i] *= sf;
#pragma unroll
        for (int jd = 0; jd < 4; ++jd)
#pragma unroll
          for (int r = 0; r < 4; ++r) o_s[i][jd][r] *= sf;
      }
      float pf = 0.f;
#pragma unroll
      for (int f = 0; f < 4; ++f) {
        bf16x4v pk;
#pragma unroll
        for (int r = 0; r < 4; ++r) {
          const float p = __builtin_amdgcn_exp2f(s[i][f][r] - m_s[i]);
          pf += p;
          pk[r] = (bf16_t)p;
        }
        *(bf16x4v*)&Pb[i * 1024 + c * 64 + ((f * 16 + g * 4) ^ sc)] = pk;
      }
      l_s[i] += pf;
    }
  };

  // O^T += V^T @ P for one branch (16 MFMA)
  auto pv = [&](const bf16_t* Vt, const bf16_t* Pb, f32x4 (&o_s)[2][4]) {
    bf16x8 pa[2][2];
#pragma unroll
    for (int i = 0; i < 2; ++i) {
      pa[i][0] = *(const bf16x8*)&Pb[i * 1024 + c * 64 + ((g * 8) ^ sc)];
      pa[i][1] = *(const bf16x8*)&Pb[i * 1024 + c * 64 + ((32 + g * 8) ^ sc)];
    }
#pragma unroll
    for (int jd = 0; jd < 4; ++jd) {
      const bf16x8 v0 = *(const bf16x8*)&Vt[(jd * 16 + c) * 64 + ((g * 8) ^ sc)];
      const bf16x8 v1 = *(const bf16x8*)&Vt[(jd * 16 + c) * 64 + ((32 + g * 8) ^ sc)];
#pragma unroll
      for (int i = 0; i < 2; ++i) {
        o_s[i][jd] = __builtin_amdgcn_mfma_f32_16x16x32_bf16(v0, pa[i][0], o_s[i][jd], 0, 0, 0);
        o_s[i][jd] = __builtin_amdgcn_mfma_f32_16x16x32_bf16(v1, pa[i][1], o_s[i][jd], 0, 0, 0);
      }
    }
  };

  for (int t = 0; t < 16; ++t) {
    const int kv0 = t * 64;
    if (t) __syncthreads();   // previous compute done before overwriting tiles
#pragma unroll
    for (int p = 0; p < 2; ++p) {
      const int row = w * 16 + p * 8;
      gload_lds16(kp  + (size_t)(kv0 + row + lrow) * DKH + lcol, &Ks[row * 64]);
      gload_lds16(rkp + (size_t)(kv0 + row + lrow) * DKH + lcol, &RKs[row * 64]);
      gload_lds16(vp  + (size_t)(row + lrow) * SEQ + kv0 + lcol, &Vs[row * 64]);
      gload_lds16(rvp + (size_t)(row + lrow) * SEQ + kv0 + lcol, &RVs[row * 64]);
    }
    __syncthreads();          // tiles (and Mb, at t=0) ready

    f32x4 mb[4];
#pragma unroll
    for (int f = 0; f < 4; ++f)
      mb[f] = *(const f32x4*)&Mb[kv0 + f * 16 + g * 4];

    // both softmaxes first (each P turnaround covered by following work),
    // then the 32 PV MFMAs as one cluster under raised priority
    qk_sm(Ks,  Pwv, mb, mv, lv, ov);
    qk_sm(RKs, Pwr, mb, mr, lr, orl);
    __builtin_amdgcn_s_setprio(1);
    pv(Vs,  Pwv, ov);
    pv(RVs, Pwr, orl);
    __builtin_amdgcn_s_setprio(0);
  }

  // denominators: reduce per-lane partials across the 4 g-groups
#pragma unroll
  for (int i = 0; i < 2; ++i) {
    lv[i] += __shfl_xor(lv[i], 16); lv[i] += __shfl_xor(lv[i], 32);
    lr[i] += __shfl_xor(lr[i], 16); lr[i] += __shfl_xor(lr[i], 32);
  }

  bf16_t* xb = x + (size_t)b * SEQ * DMODEL + (size_t)h * DKH;
#pragma unroll
  for (int i = 0; i < 2; ++i) {
    const float rlv = 1.0f / lv[i], rlr = 1.0f / lr[i];
    const int qrow = q0 + w * 32 + i * 16 + c;
#pragma unroll
    for (int jd = 0; jd < 4; ++jd) {
      bf16x4v pk;
#pragma unroll
      for (int r = 0; r < 4; ++r)
        pk[r] = (bf16_t)(ov[i][jd][r] * rlv + orl[i][jd][r] * rlr);
      *(bf16x4v*)&xb[(size_t)qrow * DMODEL + jd * 16 + g * 4] = pk;
    }
  }
}

// ---------------- host launch ---------------------------------------------
extern "C" void kernel_launch(void* const* d_in, const int* in_sizes, int n_in,
                              void* d_out, int out_size, void* d_ws, size_t ws_size,
                              hipStream_t stream) {
  (void)in_sizes; (void)n_in; (void)out_size; (void)ws_size;
  const float* query = (const float*)d_in[0];
  const float* key_  = (const float*)d_in[1];
  const float* value = (const float*)d_in[2];
  const float* weak  = (const float*)d_in[3];
  const int*   mask  = (const int*)d_in[4];
  const float* Wq  = (const float*)d_in[5];  const float* bq  = (const float*)d_in[6];
  const float* Wk  = (const float*)d_in[7];  const float* bk  = (const float*)d_in[8];
  const float* Wv  = (const float*)d_in[9];  const float* bv  = (const float*)d_in[10];
  const float* Wrk = (const float*)d_in[11]; const float* brk = (const float*)d_in[12];
  const float* Wrv = (const float*)d_in[13]; const float* brv = (const float*)d_in[14];
  const float* Wo  = (const float*)d_in[15]; const float* bo  = (const float*)d_in[16];

  char* ws = (char*)d_ws;
  size_t off = 0;
  auto alloc = [&](size_t bytes) {
    void* p = ws + off;
    off += (bytes + 255) & ~(size_t)255;
    return p;
  };
  const size_t SZ_X = NXE * sizeof(bf16_t); // 8 MB (256-aligned -> contiguous)
  const size_t SZ_W = NWE * sizeof(bf16_t); // 2 MB

  // X segments contiguous (q,k,v,r), W segments contiguous (q,k,v,rk,rv,o),
  // proj outputs contiguous (qh,kh,rkh,vTh,rvTh) -- proj_gemm indexes by base.
  bf16_t* Xq = (bf16_t*)alloc(SZ_X);
  bf16_t* Xk = (bf16_t*)alloc(SZ_X);
  bf16_t* Xv = (bf16_t*)alloc(SZ_X);
  bf16_t* Xr = (bf16_t*)alloc(SZ_X);
  bf16_t* Wqb  = (bf16_t*)alloc(SZ_W);
  bf16_t* Wkb  = (bf16_t*)alloc(SZ_W);
  bf16_t* Wvb  = (bf16_t*)alloc(SZ_W);
  bf16_t* Wrkb = (bf16_t*)alloc(SZ_W);
  bf16_t* Wrvb = (bf16_t*)alloc(SZ_W);
  bf16_t* Wob  = (bf16_t*)alloc(SZ_W);
  bf16_t* qh   = (bf16_t*)alloc(SZ_X);
  bf16_t* kh   = (bf16_t*)alloc(SZ_X);
  bf16_t* rkh  = (bf16_t*)alloc(SZ_X);
  bf16_t* vTh  = (bf16_t*)alloc(SZ_X);
  bf16_t* rvTh = (bf16_t*)alloc(SZ_X);
  bf16_t* xh   = (bf16_t*)alloc(SZ_X);
  (void)Xk; (void)Xv; (void)Xr; (void)Wkb; (void)Wvb; (void)Wrkb; (void)Wrvb;
  (void)kh; (void)rkh; (void)vTh; (void)rvTh;

  // f32 -> bf16
  cvt_multi<<<dim3(4096, 4), 256, 0, stream>>>(query, key_, value, weak, nullptr, nullptr,
                                               Xq, Xk, Xv, Xr, nullptr, nullptr,
                                               NB * SEQ * DMODEL);
  cvt_multi<<<dim3(1024, 6), 256, 0, stream>>>(Wq, Wk, Wv, Wrk, Wrv, Wo,
                                               Wqb, Wkb, Wvb, Wrkb, Wrvb, Wob,
                                               DMODEL * DMODEL);

  // all 5 projections in one grouped dispatch (1280 blocks, 128x128 tiles)
  proj_gemm<<<dim3(1280), 256, 0, stream>>>(Xq, Wqb, qh, bq, bk, bv, brk, brv);

  // fused dual attention: 512 blocks, 68KB dynamic LDS (2 blocks/CU)
  attn_kernel<<<dim3(512), 256, 69632, stream>>>(qh, kh, rkh, vTh, rvTh, mask, xh);

  // output projection -> f32 d_out (256 blocks, 128x128 tiles)
  out_gemm<<<dim3(256), 256, 0, stream>>>(xh, Wob, bo, (float*)d_out);
}

// Round 13
// 164.541 us; speedup vs baseline: 1.0877x; 1.0026x over previous
//
#include <hip/hip_runtime.h>
#include <stdint.h>

#define NB 4
#define NH 16
#define DKH 64
#define DMODEL 1024
#define SEQ 1024
#define SCALE 0.125f
#define NEG_INF -1.0e9f
#define K2E 0.18033688011112042f  // SCALE * log2(e): softmax in exp2 domain

typedef __bf16 bf16_t;
typedef __bf16 bf16x8 __attribute__((ext_vector_type(8)));
typedef __bf16 bf16x4v __attribute__((ext_vector_type(4)));
typedef float f32x4 __attribute__((ext_vector_type(4)));
typedef uint32_t u32x4 __attribute__((ext_vector_type(4)));

typedef const uint32_t __attribute__((address_space(1)))* gas_ptr;
typedef uint32_t __attribute__((address_space(3)))* las_ptr;

// async global->LDS, 16B per lane, dest = wave-uniform base + lane*16
__device__ __forceinline__ void gload_lds16(const void* g, void* l) {
  __builtin_amdgcn_global_load_lds((gas_ptr)g, (las_ptr)l, 16, 0, 0);
}

// T2 XOR swizzle for [R][64] bf16 tiles: element col ^= (row&7)<<3.
// Journal: R2 swizzle: conflicts 1.99e7->0. R4 (256,4)->spill; (256,2) sane.
// R6 reg-interleave HURT. R7 32q/wave shared frags: 77.9. R8 split / R9
// 2-phase(gload_lds) / R10 32x32: regressed. R11 +mask-bias+defer-max: 76.7.
// R12 reorder+setprio: 75.3. P-store "conflicts" = structural b64 floor.
// R13 = T14 async-STAGE: reg-stage K/V (global->reg early, ds_write late) so
// neither barrier waits on HBM -- gload_lds prefetch CANNOT survive a barrier
// (vmcnt(0) drain, the m97 stall; root cause of R3/R9 failures).

// ---------------- f32 -> bf16 conversion (select tensor by blockIdx.y) ----
__global__ void cvt_multi(const float* __restrict__ i0, const float* __restrict__ i1,
                          const float* __restrict__ i2, const float* __restrict__ i3,
                          const float* __restrict__ i4, const float* __restrict__ i5,
                          bf16_t* o0, bf16_t* o1, bf16_t* o2, bf16_t* o3, bf16_t* o4, bf16_t* o5,
                          int n) {
  const int t = blockIdx.y;
  const float* in = (t == 0) ? i0 : (t == 1) ? i1 : (t == 2) ? i2 : (t == 3) ? i3 : (t == 4) ? i4 : i5;
  bf16_t* out = (t == 0) ? o0 : (t == 1) ? o1 : (t == 2) ? o2 : (t == 3) ? o3 : (t == 4) ? o4 : o5;
  const int idx = (blockIdx.x * 256 + threadIdx.x) * 4;
  if (idx >= n) return;
  const float4 v = *(const float4*)(in + idx);
  bf16x4v p;
  p[0] = (bf16_t)v.x; p[1] = (bf16_t)v.y; p[2] = (bf16_t)v.z; p[3] = (bf16_t)v.w;
  *(bf16x4v*)(out + idx) = p;
}

// ---------------- 128x128-tile GEMM core (m97 structure) -------------------
#define NXE ((size_t)NB * SEQ * DMODEL)      // elements per X/out segment
#define NWE ((size_t)DMODEL * DMODEL)

template<int MODE>
__device__ __forceinline__ void gemm128_body(
    const bf16_t* __restrict__ A, const bf16_t* __restrict__ W,
    const float* __restrict__ bias, void* __restrict__ outp,
    int m0, int n0, bf16_t* As, bf16_t* Bs) {
  const int tid = threadIdx.x;
  const int lane = tid & 63;
  const int w = tid >> 6;
  const int wm = w >> 1, wn = w & 1;
  const int g = lane >> 4, c = lane & 15;
  const int lrow = lane >> 3;
  const int lcol = ((lane & 7) * 8) ^ ((lane >> 3) << 3);  // pre-swizzled source col
  const int sc = (c & 7) << 3;                             // read-side XOR

  f32x4 acc[4][4] = {};

  for (int kt = 0; kt < DMODEL; kt += 64) {
#pragma unroll
    for (int p = 0; p < 4; ++p) {
      const int row = w * 32 + p * 8;
      gload_lds16(A + (size_t)(m0 + row + lrow) * DMODEL + kt + lcol, &As[row * 64]);
      gload_lds16(W + (size_t)(n0 + row + lrow) * DMODEL + kt + lcol, &Bs[row * 64]);
    }
    __syncthreads();
    bf16x8 af[4][2], bfr[4][2];
#pragma unroll
    for (int i = 0; i < 4; ++i)
#pragma unroll
      for (int kk = 0; kk < 2; ++kk) {
        af[i][kk]  = *(const bf16x8*)&As[(wm * 64 + i * 16 + c) * 64 + ((kk * 32 + g * 8) ^ sc)];
        bfr[i][kk] = *(const bf16x8*)&Bs[(wn * 64 + i * 16 + c) * 64 + ((kk * 32 + g * 8) ^ sc)];
      }
#pragma unroll
    for (int i = 0; i < 4; ++i)
#pragma unroll
      for (int j = 0; j < 4; ++j) {
        acc[i][j] = __builtin_amdgcn_mfma_f32_16x16x32_bf16(af[i][0], bfr[j][0], acc[i][j], 0, 0, 0);
        acc[i][j] = __builtin_amdgcn_mfma_f32_16x16x32_bf16(af[i][1], bfr[j][1], acc[i][j], 0, 0, 0);
      }
    __syncthreads();
  }

  float bv4[4];
#pragma unroll
  for (int j = 0; j < 4; ++j) bv4[j] = bias[n0 + wn * 64 + j * 16 + c];

#pragma unroll
  for (int i = 0; i < 4; ++i) {
    const int mrow = m0 + wm * 64 + i * 16 + g * 4;   // C-layout: row = g*4 + r
    const int b_ = mrow >> 10, l_ = mrow & 1023;
#pragma unroll
    for (int j = 0; j < 4; ++j) {
      const int n = n0 + wn * 64 + j * 16 + c;        // C-layout: col = lane&15
      if (MODE == 2) {
        float* o = (float*)outp;
#pragma unroll
        for (int r = 0; r < 4; ++r)
          o[(size_t)(mrow + r) * DMODEL + n] = acc[i][j][r] + bv4[j];
      } else if (MODE == 0) {
        bf16_t* o = (bf16_t*)outp;
        const int h_ = n >> 6, dk_ = n & 63;
#pragma unroll
        for (int r = 0; r < 4; ++r)
          o[((size_t)(b_ * NH + h_) * SEQ + l_ + r) * DKH + dk_] =
              (bf16_t)(acc[i][j][r] + bv4[j]);
      } else { // MODE 1: transposed [B,H,DK,L]; 4 consecutive l -> packed 8B store
        bf16_t* o = (bf16_t*)outp;
        const int h_ = n >> 6, dk_ = n & 63;
        bf16x4v pk;
#pragma unroll
        for (int r = 0; r < 4; ++r) pk[r] = (bf16_t)(acc[i][j][r] + bv4[j]);
        *(bf16x4v*)&o[((size_t)(b_ * NH + h_) * DKH + dk_) * SEQ + l_] = pk;
      }
    }
  }
}

// grouped projection: 5 segments x (32 m-tiles x 8 n-tiles) = 1280 blocks
__global__ void __launch_bounds__(256, 2)
proj_gemm(const bf16_t* __restrict__ Xbase, const bf16_t* __restrict__ Wbase,
          bf16_t* __restrict__ Obase,
          const float* __restrict__ b0, const float* __restrict__ b1,
          const float* __restrict__ b2, const float* __restrict__ b3,
          const float* __restrict__ b4) {
  __shared__ bf16_t As[128 * 64];
  __shared__ bf16_t Bs[128 * 64];
  const int bid = blockIdx.x;
  const int lid = (bid & 7) * 160 + (bid >> 3);   // T1 swizzle (1280 % 8 == 0)
  const int seg = lid >> 8;                       // 0..4
  const int rr = lid & 255;
  const int m0 = (rr >> 3) * 128, n0 = (rr & 7) * 128;

  const bf16_t* A = Xbase + (size_t)((seg < 3) ? seg : 3) * NXE;
  const bf16_t* W = Wbase + (size_t)seg * NWE;
  const int ooff = (seg == 0) ? 0 : (seg == 1) ? 1 : (seg == 2) ? 3 : (seg == 3) ? 2 : 4;
  bf16_t* out = Obase + (size_t)ooff * NXE;
  const float* bias = (seg == 0) ? b0 : (seg == 1) ? b1 : (seg == 2) ? b2 : (seg == 3) ? b3 : b4;

  if (seg == 2 || seg == 4) gemm128_body<1>(A, W, bias, out, m0, n0, As, Bs);
  else                      gemm128_body<0>(A, W, bias, out, m0, n0, As, Bs);
}

// output projection -> f32 d_out: 32 x 8 = 256 blocks
__global__ void __launch_bounds__(256, 2)
out_gemm(const bf16_t* __restrict__ A, const bf16_t* __restrict__ W,
         const float* __restrict__ bias, float* __restrict__ out) {
  __shared__ bf16_t As[128 * 64];
  __shared__ bf16_t Bs[128 * 64];
  const int bid = blockIdx.x;
  const int lid = (bid & 7) * 32 + (bid >> 3);    // T1 swizzle (256 % 8 == 0)
  const int m0 = (lid >> 3) * 128, n0 = (lid & 7) * 128;
  gemm128_body<2>(A, W, bias, out, m0, n0, As, Bs);
}

// ---------------- fused dual flash attention (R13: T14 async-STAGE) --------
// R12 compute structure; staging is now global->REG (issued before compute,
// HBM latency hides under it) + ds_write after the post-compute barrier
// (second barrier waits on lgkm only, never HBM).
__global__ void __launch_bounds__(256, 2)
attn_kernel(const bf16_t* __restrict__ q, const bf16_t* __restrict__ k,
            const bf16_t* __restrict__ rk, const bf16_t* __restrict__ vT,
            const bf16_t* __restrict__ rvT, const int* __restrict__ mask,
            bf16_t* __restrict__ x) {
  extern __shared__ __align__(256) bf16_t smem[];
  bf16_t* Ks  = smem;                 // 8KB
  bf16_t* RKs = Ks  + 64 * 64;        // 8KB
  bf16_t* Vs  = RKs + 64 * 64;        // 8KB
  bf16_t* RVs = Vs  + 64 * 64;        // 8KB
  bf16_t* Pbase = RVs + 64 * 64;      // 4 waves x 2 branches x 2048 = 32KB
  float* Mb = (float*)(Pbase + 8 * 2048);  // 4KB -> total 68KB

  const int tid = threadIdx.x;
  const int lane = tid & 63;
  const int w = tid >> 6;
  const int g = lane >> 4, c = lane & 15;
  const int sc = (c & 7) << 3;
  const int bid = blockIdx.x;
  const int lid = (bid & 7) * 64 + (bid >> 3);   // T1 swizzle (512 % 8 == 0)
  const int qt = lid & 7;
  const int bh = lid >> 3;
  const int b = bh >> 4, h = bh & 15;
  const int q0 = qt * 128;

  const bf16_t* qp = q + (size_t)bh * SEQ * DKH;
  const bf16_t* kp = k + (size_t)bh * SEQ * DKH;
  const bf16_t* rkp = rk + (size_t)bh * SEQ * DKH;
  const bf16_t* vp = vT + (size_t)bh * DKH * SEQ;
  const bf16_t* rvp = rvT + (size_t)bh * DKH * SEQ;
  const int* mp = mask + b * SEQ;

  // reg-staging thread map: per tensor, p=0..1 chunks; LINEAR global col,
  // XOR swizzle applied on the LDS WRITE side (both-sides involution kept).
  const int lrow = lane >> 3;
  const int lcolL = (lane & 7) * 8;                        // linear source col
  const int wcol = lcolL ^ (((w * 16 + lrow) & 7) << 3);   // (row&7) per p is same: rows differ by 8

  bf16_t* Pwv = Pbase + w * 2048;            // [2 halves][16 q][64 kv]
  bf16_t* Pwr = Pbase + (4 + w) * 2048;

  // mask bias table (published by the prologue barrier)
#pragma unroll
  for (int i = 0; i < 4; ++i) {
    const int idx = i * 256 + tid;
    Mb[idx] = (mp[idx] == 0) ? NEG_INF : 0.0f;
  }

  // Q fragments in registers: wave owns 32 q-rows as two 16-col B-fragments
  bf16x8 qf[2][2];
#pragma unroll
  for (int i = 0; i < 2; ++i)
#pragma unroll
    for (int kk = 0; kk < 2; ++kk)
      qf[i][kk] = *(const bf16x8*)(qp + (size_t)(q0 + w * 32 + i * 16 + c) * DKH + kk * 32 + g * 8);

  f32x4 ov[2][4] = {}, orl[2][4] = {};
  float mv[2] = {NEG_INF, NEG_INF}, mr[2] = {NEG_INF, NEG_INF};
  float lv[2] = {0.f, 0.f}, lr[2] = {0.f, 0.f};

  // staged tile registers: [tensor 0..3][p 0..1] 16B each = 32 VGPR
  u32x4 st[4][2];

  auto ldreg = [&](int kv0) {
#pragma unroll
    for (int p = 0; p < 2; ++p) {
      const int row = w * 16 + p * 8 + lrow;
      st[0][p] = *(const u32x4*)(kp  + (size_t)(kv0 + row) * DKH + lcolL);
      st[1][p] = *(const u32x4*)(rkp + (size_t)(kv0 + row) * DKH + lcolL);
      st[2][p] = *(const u32x4*)(vp  + (size_t)row * SEQ + kv0 + lcolL);
      st[3][p] = *(const u32x4*)(rvp + (size_t)row * SEQ + kv0 + lcolL);
    }
  };
  auto wrlds = [&]() {
#pragma unroll
    for (int p = 0; p < 2; ++p) {
      const int row = w * 16 + p * 8 + lrow;
      *(u32x4*)&Ks [row * 64 + wcol] = st[0][p];
      *(u32x4*)&RKs[row * 64 + wcol] = st[1][p];
      *(u32x4*)&Vs [row * 64 + wcol] = st[2][p];
      *(u32x4*)&RVs[row * 64 + wcol] = st[3][p];
    }
  };

  // QK^T + online softmax + P write for one branch
  auto qk_sm = [&](const bf16_t* Kt, bf16_t* Pb, const f32x4 (&mb)[4],
                   float (&m_s)[2], float (&l_s)[2], f32x4 (&o_s)[2][4]) {
    f32x4 s[2][4];
    {
      bf16x8 kfr[4][2];
#pragma unroll
      for (int f = 0; f < 4; ++f) {
        kfr[f][0] = *(const bf16x8*)&Kt[(f * 16 + c) * 64 + ((g * 8) ^ sc)];
        kfr[f][1] = *(const bf16x8*)&Kt[(f * 16 + c) * 64 + ((32 + g * 8) ^ sc)];
      }
#pragma unroll
      for (int i = 0; i < 2; ++i)
#pragma unroll
        for (int f = 0; f < 4; ++f) {
          f32x4 a = {0.f, 0.f, 0.f, 0.f};
          a = __builtin_amdgcn_mfma_f32_16x16x32_bf16(kfr[f][0], qf[i][0], a, 0, 0, 0);
          a = __builtin_amdgcn_mfma_f32_16x16x32_bf16(kfr[f][1], qf[i][1], a, 0, 0, 0);
          s[i][f] = a;
        }
    } // kfr dead -> caps register peak

#pragma unroll
    for (int i = 0; i < 2; ++i)
#pragma unroll
      for (int f = 0; f < 4; ++f)
#pragma unroll
        for (int r = 0; r < 4; ++r)
          s[i][f][r] = s[i][f][r] * K2E + mb[f][r];

#pragma unroll
    for (int i = 0; i < 2; ++i) {
      float tm = fmaxf(fmaxf(s[i][0][0], s[i][0][1]), fmaxf(s[i][0][2], s[i][0][3]));
#pragma unroll
      for (int f = 1; f < 4; ++f)
        tm = fmaxf(tm, fmaxf(fmaxf(s[i][f][0], s[i][f][1]), fmaxf(s[i][f][2], s[i][f][3])));
      tm = fmaxf(tm, __shfl_xor(tm, 16));
      tm = fmaxf(tm, __shfl_xor(tm, 32));
      if (!__all(tm <= m_s[i] + 8.0f)) {   // defer-max: rescale only on real growth
        const float mnew = fmaxf(m_s[i], tm);
        const float sf = __builtin_amdgcn_exp2f(m_s[i] - mnew);
        m_s[i] = mnew;
        l_s[i] *= sf;
#pragma unroll
        for (int jd = 0; jd < 4; ++jd)
#pragma unroll
          for (int r = 0; r < 4; ++r) o_s[i][jd][r] *= sf;
      }
      float pf = 0.f;
#pragma unroll
      for (int f = 0; f < 4; ++f) {
        bf16x4v pk;
#pragma unroll
        for (int r = 0; r < 4; ++r) {
          const float p = __builtin_amdgcn_exp2f(s[i][f][r] - m_s[i]);
          pf += p;
          pk[r] = (bf16_t)p;
        }
        *(bf16x4v*)&Pb[i * 1024 + c * 64 + ((f * 16 + g * 4) ^ sc)] = pk;
      }
      l_s[i] += pf;
    }
  };

  // O^T += V^T @ P for one branch (16 MFMA)
  auto pv = [&](const bf16_t* Vt, const bf16_t* Pb, f32x4 (&o_s)[2][4]) {
    bf16x8 pa[2][2];
#pragma unroll
    for (int i = 0; i < 2; ++i) {
      pa[i][0] = *(const bf16x8*)&Pb[i * 1024 + c * 64 + ((g * 8) ^ sc)];
      pa[i][1] = *(const bf16x8*)&Pb[i * 1024 + c * 64 + ((32 + g * 8) ^ sc)];
    }
#pragma unroll
    for (int jd = 0; jd < 4; ++jd) {
      const bf16x8 v0 = *(const bf16x8*)&Vt[(jd * 16 + c) * 64 + ((g * 8) ^ sc)];
      const bf16x8 v1 = *(const bf16x8*)&Vt[(jd * 16 + c) * 64 + ((32 + g * 8) ^ sc)];
#pragma unroll
      for (int i = 0; i < 2; ++i) {
        o_s[i][jd] = __builtin_amdgcn_mfma_f32_16x16x32_bf16(v0, pa[i][0], o_s[i][jd], 0, 0, 0);
        o_s[i][jd] = __builtin_amdgcn_mfma_f32_16x16x32_bf16(v1, pa[i][1], o_s[i][jd], 0, 0, 0);
      }
    }
  };

  // prologue: stage tile 0 through registers, publish, barrier (also Mb)
  ldreg(0);
  wrlds();
  __syncthreads();

  for (int t = 0; t < 16; ++t) {
    const int kv0 = t * 64;

    // T14 issue-early: next tile's global loads ride under this tile's compute
    if (t < 15) ldreg(kv0 + 64);

    f32x4 mb[4];
#pragma unroll
    for (int f = 0; f < 4; ++f)
      mb[f] = *(const f32x4*)&Mb[kv0 + f * 16 + g * 4];

    qk_sm(Ks,  Pwv, mb, mv, lv, ov);
    qk_sm(RKs, Pwr, mb, mr, lr, orl);
    __builtin_amdgcn_s_setprio(1);
    pv(Vs,  Pwv, ov);
    pv(RVs, Pwr, orl);
    __builtin_amdgcn_s_setprio(0);

    if (t < 15) {
      __syncthreads();   // all reads of tile t done (compute-bound wait, no HBM)
      wrlds();           // vmcnt waits happened here, loads long since landed
      __syncthreads();   // publish tile t+1 (lgkm-only drain, ~100 cyc)
    }
  }

  // denominators: reduce per-lane partials across the 4 g-groups
#pragma unroll
  for (int i = 0; i < 2; ++i) {
    lv[i] += __shfl_xor(lv[i], 16); lv[i] += __shfl_xor(lv[i], 32);
    lr[i] += __shfl_xor(lr[i], 16); lr[i] += __shfl_xor(lr[i], 32);
  }

  bf16_t* xb = x + (size_t)b * SEQ * DMODEL + (size_t)h * DKH;
#pragma unroll
  for (int i = 0; i < 2; ++i) {
    const float rlv = 1.0f / lv[i], rlr = 1.0f / lr[i];
    const int qrow = q0 + w * 32 + i * 16 + c;
#pragma unroll
    for (int jd = 0; jd < 4; ++jd) {
      bf16x4v pk;
#pragma unroll
      for (int r = 0; r < 4; ++r)
        pk[r] = (bf16_t)(ov[i][jd][r] * rlv + orl[i][jd][r] * rlr);
      *(bf16x4v*)&xb[(size_t)qrow * DMODEL + jd * 16 + g * 4] = pk;
    }
  }
}

// ---------------- host launch ---------------------------------------------
extern "C" void kernel_launch(void* const* d_in, const int* in_sizes, int n_in,
                              void* d_out, int out_size, void* d_ws, size_t ws_size,
                              hipStream_t stream) {
  (void)in_sizes; (void)n_in; (void)out_size; (void)ws_size;
  const float* query = (const float*)d_in[0];
  const float* key_  = (const float*)d_in[1];
  const float* value = (const float*)d_in[2];
  const float* weak  = (const float*)d_in[3];
  const int*   mask  = (const int*)d_in[4];
  const float* Wq  = (const float*)d_in[5];  const float* bq  = (const float*)d_in[6];
  const float* Wk  = (const float*)d_in[7];  const float* bk  = (const float*)d_in[8];
  const float* Wv  = (const float*)d_in[9];  const float* bv  = (const float*)d_in[10];
  const float* Wrk = (const float*)d_in[11]; const float* brk = (const float*)d_in[12];
  const float* Wrv = (const float*)d_in[13]; const float* brv = (const float*)d_in[14];
  const float* Wo  = (const float*)d_in[15]; const float* bo  = (const float*)d_in[16];

  char* ws = (char*)d_ws;
  size_t off = 0;
  auto alloc = [&](size_t bytes) {
    void* p = ws + off;
    off += (bytes + 255) & ~(size_t)255;
    return p;
  };
  const size_t SZ_X = NXE * sizeof(bf16_t); // 8 MB (256-aligned -> contiguous)
  const size_t SZ_W = NWE * sizeof(bf16_t); // 2 MB

  // X segments contiguous (q,k,v,r), W segments contiguous (q,k,v,rk,rv,o),
  // proj outputs contiguous (qh,kh,rkh,vTh,rvTh) -- proj_gemm indexes by base.
  bf16_t* Xq = (bf16_t*)alloc(SZ_X);
  bf16_t* Xk = (bf16_t*)alloc(SZ_X);
  bf16_t* Xv = (bf16_t*)alloc(SZ_X);
  bf16_t* Xr = (bf16_t*)alloc(SZ_X);
  bf16_t* Wqb  = (bf16_t*)alloc(SZ_W);
  bf16_t* Wkb  = (bf16_t*)alloc(SZ_W);
  bf16_t* Wvb  = (bf16_t*)alloc(SZ_W);
  bf16_t* Wrkb = (bf16_t*)alloc(SZ_W);
  bf16_t* Wrvb = (bf16_t*)alloc(SZ_W);
  bf16_t* Wob  = (bf16_t*)alloc(SZ_W);
  bf16_t* qh   = (bf16_t*)alloc(SZ_X);
  bf16_t* kh   = (bf16_t*)alloc(SZ_X);
  bf16_t* rkh  = (bf16_t*)alloc(SZ_X);
  bf16_t* vTh  = (bf16_t*)alloc(SZ_X);
  bf16_t* rvTh = (bf16_t*)alloc(SZ_X);
  bf16_t* xh   = (bf16_t*)alloc(SZ_X);
  (void)Xk; (void)Xv; (void)Xr; (void)Wkb; (void)Wvb; (void)Wrkb; (void)Wrvb;
  (void)kh; (void)rkh; (void)vTh; (void)rvTh;

  // f32 -> bf16
  cvt_multi<<<dim3(4096, 4), 256, 0, stream>>>(query, key_, value, weak, nullptr, nullptr,
                                               Xq, Xk, Xv, Xr, nullptr, nullptr,
                                               NB * SEQ * DMODEL);
  cvt_multi<<<dim3(1024, 6), 256, 0, stream>>>(Wq, Wk, Wv, Wrk, Wrv, Wo,
                                               Wqb, Wkb, Wvb, Wrkb, Wrvb, Wob,
                                               DMODEL * DMODEL);

  // all 5 projections in one grouped dispatch (1280 blocks, 128x128 tiles)
  proj_gemm<<<dim3(1280), 256, 0, stream>>>(Xq, Wqb, qh, bq, bk, bv, brk, brv);

  // fused dual attention: 512 blocks, 68KB dynamic LDS (2 blocks/CU)
  attn_kernel<<<dim3(512), 256, 69632, stream>>>(qh, kh, rkh, vTh, rvTh, mask, xh);

  // output projection -> f32 d_out (256 blocks, 128x128 tiles)
  out_gemm<<<dim3(256), 256, 0, stream>>>(xh, Wob, bo, (float*)d_out);
}

// Round 14
// 161.673 us; speedup vs baseline: 1.1070x; 1.0177x over previous
//
#include <hip/hip_runtime.h>
#include <stdint.h>

#define NB 4
#define NH 16
#define DKH 64
#define DMODEL 1024
#define SEQ 1024
#define SCALE 0.125f
#define NEG_INF -1.0e9f
#define K2E 0.18033688011112042f  // SCALE * log2(e): softmax in exp2 domain

typedef __bf16 bf16_t;
typedef __bf16 bf16x8 __attribute__((ext_vector_type(8)));
typedef __bf16 bf16x4v __attribute__((ext_vector_type(4)));
typedef float f32x4 __attribute__((ext_vector_type(4)));
typedef uint32_t u32x4 __attribute__((ext_vector_type(4)));

typedef const uint32_t __attribute__((address_space(1)))* gas_ptr;
typedef uint32_t __attribute__((address_space(3)))* las_ptr;

// async global->LDS, 16B per lane, dest = wave-uniform base + lane*16
__device__ __forceinline__ void gload_lds16(const void* g, void* l) {
  __builtin_amdgcn_global_load_lds((gas_ptr)g, (las_ptr)l, 16, 0, 0);
}

// T2 XOR swizzle for [R][64] bf16 tiles: element col ^= (row&7)<<3.
// Journal: R2 swizzle: conflicts 1.99e7->0. R4 (256,4)->spill; (256,2) sane.
// R6 reg-interleave HURT. R7 32q/wave shared frags: 77.9. R8 split / R9
// 2-phase(gload_lds) / R10 32x32: regressed. R11 +mask-bias+defer-max: 76.7.
// R12 reorder+setprio(PV): 75.3. R13 T14 async-STAGE (reg-stage, lgkm-only
// barriers): 71.0. Attn is GRID-CAPPED at 2 waves/SIMD (64K q-rows / 32
// q/wave = 2048 waves); structural floor for this decomposition. R14:
// consolidation -- out_gemm 128x64 (2/CU), fused cvt, setprio on QK.

#define NXE ((size_t)NB * SEQ * DMODEL)      // elements per X/out segment
#define NWE ((size_t)DMODEL * DMODEL)

// ---------------- fused f32 -> bf16 conversion (X tensors + W tensors) -----
__global__ void cvt_all(const float* __restrict__ x0, const float* __restrict__ x1,
                        const float* __restrict__ x2, const float* __restrict__ x3,
                        const float* __restrict__ w0, const float* __restrict__ w1,
                        const float* __restrict__ w2, const float* __restrict__ w3,
                        const float* __restrict__ w4, const float* __restrict__ w5,
                        bf16_t* __restrict__ Xbase, bf16_t* __restrict__ Wbase) {
  const int y = blockIdx.y;
  const float* in;
  bf16_t* out;
  int n;
  if (y < 4) {
    in = (y == 0) ? x0 : (y == 1) ? x1 : (y == 2) ? x2 : x3;
    out = Xbase + (size_t)y * NXE;
    n = (int)NXE;
  } else {
    const int j = y - 4;
    in = (j == 0) ? w0 : (j == 1) ? w1 : (j == 2) ? w2 : (j == 3) ? w3 : (j == 4) ? w4 : w5;
    out = Wbase + (size_t)j * NWE;
    n = (int)NWE;
  }
  const int idx = (blockIdx.x * 256 + threadIdx.x) * 4;
  if (idx >= n) return;
  const float4 v = *(const float4*)(in + idx);
  bf16x4v p;
  p[0] = (bf16_t)v.x; p[1] = (bf16_t)v.y; p[2] = (bf16_t)v.z; p[3] = (bf16_t)v.w;
  *(bf16x4v*)(out + idx) = p;
}

// ---------------- 128x128-tile GEMM core (m97 structure) -------------------
template<int MODE>
__device__ __forceinline__ void gemm128_body(
    const bf16_t* __restrict__ A, const bf16_t* __restrict__ W,
    const float* __restrict__ bias, void* __restrict__ outp,
    int m0, int n0, bf16_t* As, bf16_t* Bs) {
  const int tid = threadIdx.x;
  const int lane = tid & 63;
  const int w = tid >> 6;
  const int wm = w >> 1, wn = w & 1;
  const int g = lane >> 4, c = lane & 15;
  const int lrow = lane >> 3;
  const int lcol = ((lane & 7) * 8) ^ ((lane >> 3) << 3);  // pre-swizzled source col
  const int sc = (c & 7) << 3;                             // read-side XOR

  f32x4 acc[4][4] = {};

  for (int kt = 0; kt < DMODEL; kt += 64) {
#pragma unroll
    for (int p = 0; p < 4; ++p) {
      const int row = w * 32 + p * 8;
      gload_lds16(A + (size_t)(m0 + row + lrow) * DMODEL + kt + lcol, &As[row * 64]);
      gload_lds16(W + (size_t)(n0 + row + lrow) * DMODEL + kt + lcol, &Bs[row * 64]);
    }
    __syncthreads();
    bf16x8 af[4][2], bfr[4][2];
#pragma unroll
    for (int i = 0; i < 4; ++i)
#pragma unroll
      for (int kk = 0; kk < 2; ++kk) {
        af[i][kk]  = *(const bf16x8*)&As[(wm * 64 + i * 16 + c) * 64 + ((kk * 32 + g * 8) ^ sc)];
        bfr[i][kk] = *(const bf16x8*)&Bs[(wn * 64 + i * 16 + c) * 64 + ((kk * 32 + g * 8) ^ sc)];
      }
#pragma unroll
    for (int i = 0; i < 4; ++i)
#pragma unroll
      for (int j = 0; j < 4; ++j) {
        acc[i][j] = __builtin_amdgcn_mfma_f32_16x16x32_bf16(af[i][0], bfr[j][0], acc[i][j], 0, 0, 0);
        acc[i][j] = __builtin_amdgcn_mfma_f32_16x16x32_bf16(af[i][1], bfr[j][1], acc[i][j], 0, 0, 0);
      }
    __syncthreads();
  }

  float bv4[4];
#pragma unroll
  for (int j = 0; j < 4; ++j) bv4[j] = bias[n0 + wn * 64 + j * 16 + c];

#pragma unroll
  for (int i = 0; i < 4; ++i) {
    const int mrow = m0 + wm * 64 + i * 16 + g * 4;   // C-layout: row = g*4 + r
    const int b_ = mrow >> 10, l_ = mrow & 1023;
#pragma unroll
    for (int j = 0; j < 4; ++j) {
      const int n = n0 + wn * 64 + j * 16 + c;        // C-layout: col = lane&15
      if (MODE == 0) {
        bf16_t* o = (bf16_t*)outp;
        const int h_ = n >> 6, dk_ = n & 63;
#pragma unroll
        for (int r = 0; r < 4; ++r)
          o[((size_t)(b_ * NH + h_) * SEQ + l_ + r) * DKH + dk_] =
              (bf16_t)(acc[i][j][r] + bv4[j]);
      } else { // MODE 1: transposed [B,H,DK,L]; 4 consecutive l -> packed 8B store
        bf16_t* o = (bf16_t*)outp;
        const int h_ = n >> 6, dk_ = n & 63;
        bf16x4v pk;
#pragma unroll
        for (int r = 0; r < 4; ++r) pk[r] = (bf16_t)(acc[i][j][r] + bv4[j]);
        *(bf16x4v*)&o[((size_t)(b_ * NH + h_) * DKH + dk_) * SEQ + l_] = pk;
      }
    }
  }
}

// grouped projection: 5 segments x (32 m-tiles x 8 n-tiles) = 1280 blocks
__global__ void __launch_bounds__(256, 2)
proj_gemm(const bf16_t* __restrict__ Xbase, const bf16_t* __restrict__ Wbase,
          bf16_t* __restrict__ Obase,
          const float* __restrict__ b0, const float* __restrict__ b1,
          const float* __restrict__ b2, const float* __restrict__ b3,
          const float* __restrict__ b4) {
  __shared__ bf16_t As[128 * 64];
  __shared__ bf16_t Bs[128 * 64];
  const int bid = blockIdx.x;
  const int lid = (bid & 7) * 160 + (bid >> 3);   // T1 swizzle (1280 % 8 == 0)
  const int seg = lid >> 8;                       // 0..4
  const int rr = lid & 255;
  const int m0 = (rr >> 3) * 128, n0 = (rr & 7) * 128;

  const bf16_t* A = Xbase + (size_t)((seg < 3) ? seg : 3) * NXE;
  const bf16_t* W = Wbase + (size_t)seg * NWE;
  const int ooff = (seg == 0) ? 0 : (seg == 1) ? 1 : (seg == 2) ? 3 : (seg == 3) ? 2 : 4;
  bf16_t* out = Obase + (size_t)ooff * NXE;
  const float* bias = (seg == 0) ? b0 : (seg == 1) ? b1 : (seg == 2) ? b2 : (seg == 3) ? b3 : b4;

  if (seg == 2 || seg == 4) gemm128_body<1>(A, W, bias, out, m0, n0, As, Bs);
  else                      gemm128_body<0>(A, W, bias, out, m0, n0, As, Bs);
}

// output projection -> f32 d_out: 128x64 tiles, 512 blocks (2 blocks/CU)
__global__ void __launch_bounds__(256, 2)
out_gemm(const bf16_t* __restrict__ A, const bf16_t* __restrict__ W,
         const float* __restrict__ bias, float* __restrict__ out) {
  __shared__ bf16_t As[128 * 64];
  __shared__ bf16_t Bs[64 * 64];
  const int tid = threadIdx.x;
  const int lane = tid & 63;
  const int w = tid >> 6;
  const int wm = w >> 1, wn = w & 1;
  const int g = lane >> 4, c = lane & 15;
  const int bid = blockIdx.x;
  const int lid = (bid & 7) * 64 + (bid >> 3);   // T1 swizzle (512 % 8 == 0)
  const int bm = lid >> 4, bn = lid & 15;        // 32 x 16 tiles
  const int m0 = bm * 128, n0 = bn * 64;
  const int lrow = lane >> 3;
  const int lcol = ((lane & 7) * 8) ^ ((lane >> 3) << 3);
  const int sc = (c & 7) << 3;

  f32x4 acc[4][2] = {};

  for (int kt = 0; kt < DMODEL; kt += 64) {
#pragma unroll
    for (int p = 0; p < 4; ++p) {
      const int row = w * 32 + p * 8;
      gload_lds16(A + (size_t)(m0 + row + lrow) * DMODEL + kt + lcol, &As[row * 64]);
    }
#pragma unroll
    for (int p = 0; p < 2; ++p) {
      const int row = w * 16 + p * 8;
      gload_lds16(W + (size_t)(n0 + row + lrow) * DMODEL + kt + lcol, &Bs[row * 64]);
    }
    __syncthreads();
    bf16x8 af[4][2], bfr[2][2];
#pragma unroll
    for (int i = 0; i < 4; ++i)
#pragma unroll
      for (int kk = 0; kk < 2; ++kk)
        af[i][kk] = *(const bf16x8*)&As[(wm * 64 + i * 16 + c) * 64 + ((kk * 32 + g * 8) ^ sc)];
#pragma unroll
    for (int j = 0; j < 2; ++j)
#pragma unroll
      for (int kk = 0; kk < 2; ++kk)
        bfr[j][kk] = *(const bf16x8*)&Bs[(wn * 32 + j * 16 + c) * 64 + ((kk * 32 + g * 8) ^ sc)];
#pragma unroll
    for (int i = 0; i < 4; ++i)
#pragma unroll
      for (int j = 0; j < 2; ++j) {
        acc[i][j] = __builtin_amdgcn_mfma_f32_16x16x32_bf16(af[i][0], bfr[j][0], acc[i][j], 0, 0, 0);
        acc[i][j] = __builtin_amdgcn_mfma_f32_16x16x32_bf16(af[i][1], bfr[j][1], acc[i][j], 0, 0, 0);
      }
    __syncthreads();
  }

  float bv2[2];
#pragma unroll
  for (int j = 0; j < 2; ++j) bv2[j] = bias[n0 + wn * 32 + j * 16 + c];
#pragma unroll
  for (int i = 0; i < 4; ++i) {
    const int mrow = m0 + wm * 64 + i * 16 + g * 4;
#pragma unroll
    for (int j = 0; j < 2; ++j) {
      const int n = n0 + wn * 32 + j * 16 + c;
#pragma unroll
      for (int r = 0; r < 4; ++r)
        out[(size_t)(mrow + r) * DMODEL + n] = acc[i][j][r] + bv2[j];
    }
  }
}

// ---------------- fused dual flash attention (R13 + setprio QK) ------------
__global__ void __launch_bounds__(256, 2)
attn_kernel(const bf16_t* __restrict__ q, const bf16_t* __restrict__ k,
            const bf16_t* __restrict__ rk, const bf16_t* __restrict__ vT,
            const bf16_t* __restrict__ rvT, const int* __restrict__ mask,
            bf16_t* __restrict__ x) {
  extern __shared__ __align__(256) bf16_t smem[];
  bf16_t* Ks  = smem;                 // 8KB
  bf16_t* RKs = Ks  + 64 * 64;        // 8KB
  bf16_t* Vs  = RKs + 64 * 64;        // 8KB
  bf16_t* RVs = Vs  + 64 * 64;        // 8KB
  bf16_t* Pbase = RVs + 64 * 64;      // 4 waves x 2 branches x 2048 = 32KB
  float* Mb = (float*)(Pbase + 8 * 2048);  // 4KB -> total 68KB

  const int tid = threadIdx.x;
  const int lane = tid & 63;
  const int w = tid >> 6;
  const int g = lane >> 4, c = lane & 15;
  const int sc = (c & 7) << 3;
  const int bid = blockIdx.x;
  const int lid = (bid & 7) * 64 + (bid >> 3);   // T1 swizzle (512 % 8 == 0)
  const int qt = lid & 7;
  const int bh = lid >> 3;
  const int b = bh >> 4, h = bh & 15;
  const int q0 = qt * 128;

  const bf16_t* qp = q + (size_t)bh * SEQ * DKH;
  const bf16_t* kp = k + (size_t)bh * SEQ * DKH;
  const bf16_t* rkp = rk + (size_t)bh * SEQ * DKH;
  const bf16_t* vp = vT + (size_t)bh * DKH * SEQ;
  const bf16_t* rvp = rvT + (size_t)bh * DKH * SEQ;
  const int* mp = mask + b * SEQ;

  // reg-staging thread map: LINEAR global col, XOR swizzle on the LDS WRITE.
  const int lrow = lane >> 3;
  const int lcolL = (lane & 7) * 8;                        // linear source col
  const int wcol = lcolL ^ (((w * 16 + lrow) & 7) << 3);

  bf16_t* Pwv = Pbase + w * 2048;            // [2 halves][16 q][64 kv]
  bf16_t* Pwr = Pbase + (4 + w) * 2048;

  // mask bias table (published by the prologue barrier)
#pragma unroll
  for (int i = 0; i < 4; ++i) {
    const int idx = i * 256 + tid;
    Mb[idx] = (mp[idx] == 0) ? NEG_INF : 0.0f;
  }

  // Q fragments in registers: wave owns 32 q-rows as two 16-col B-fragments
  bf16x8 qf[2][2];
#pragma unroll
  for (int i = 0; i < 2; ++i)
#pragma unroll
    for (int kk = 0; kk < 2; ++kk)
      qf[i][kk] = *(const bf16x8*)(qp + (size_t)(q0 + w * 32 + i * 16 + c) * DKH + kk * 32 + g * 8);

  f32x4 ov[2][4] = {}, orl[2][4] = {};
  float mv[2] = {NEG_INF, NEG_INF}, mr[2] = {NEG_INF, NEG_INF};
  float lv[2] = {0.f, 0.f}, lr[2] = {0.f, 0.f};

  // staged tile registers: [tensor 0..3][p 0..1] 16B each = 32 VGPR
  u32x4 st[4][2];

  auto ldreg = [&](int kv0) {
#pragma unroll
    for (int p = 0; p < 2; ++p) {
      const int row = w * 16 + p * 8 + lrow;
      st[0][p] = *(const u32x4*)(kp  + (size_t)(kv0 + row) * DKH + lcolL);
      st[1][p] = *(const u32x4*)(rkp + (size_t)(kv0 + row) * DKH + lcolL);
      st[2][p] = *(const u32x4*)(vp  + (size_t)row * SEQ + kv0 + lcolL);
      st[3][p] = *(const u32x4*)(rvp + (size_t)row * SEQ + kv0 + lcolL);
    }
  };
  auto wrlds = [&]() {
#pragma unroll
    for (int p = 0; p < 2; ++p) {
      const int row = w * 16 + p * 8 + lrow;
      *(u32x4*)&Ks [row * 64 + wcol] = st[0][p];
      *(u32x4*)&RKs[row * 64 + wcol] = st[1][p];
      *(u32x4*)&Vs [row * 64 + wcol] = st[2][p];
      *(u32x4*)&RVs[row * 64 + wcol] = st[3][p];
    }
  };

  // QK^T + online softmax + P write for one branch
  auto qk_sm = [&](const bf16_t* Kt, bf16_t* Pb, const f32x4 (&mb)[4],
                   float (&m_s)[2], float (&l_s)[2], f32x4 (&o_s)[2][4]) {
    f32x4 s[2][4];
    {
      bf16x8 kfr[4][2];
#pragma unroll
      for (int f = 0; f < 4; ++f) {
        kfr[f][0] = *(const bf16x8*)&Kt[(f * 16 + c) * 64 + ((g * 8) ^ sc)];
        kfr[f][1] = *(const bf16x8*)&Kt[(f * 16 + c) * 64 + ((32 + g * 8) ^ sc)];
      }
      __builtin_amdgcn_s_setprio(1);
#pragma unroll
      for (int i = 0; i < 2; ++i)
#pragma unroll
        for (int f = 0; f < 4; ++f) {
          f32x4 a = {0.f, 0.f, 0.f, 0.f};
          a = __builtin_amdgcn_mfma_f32_16x16x32_bf16(kfr[f][0], qf[i][0], a, 0, 0, 0);
          a = __builtin_amdgcn_mfma_f32_16x16x32_bf16(kfr[f][1], qf[i][1], a, 0, 0, 0);
          s[i][f] = a;
        }
      __builtin_amdgcn_s_setprio(0);
    } // kfr dead -> caps register peak

#pragma unroll
    for (int i = 0; i < 2; ++i)
#pragma unroll
      for (int f = 0; f < 4; ++f)
#pragma unroll
        for (int r = 0; r < 4; ++r)
          s[i][f][r] = s[i][f][r] * K2E + mb[f][r];

#pragma unroll
    for (int i = 0; i < 2; ++i) {
      float tm = fmaxf(fmaxf(s[i][0][0], s[i][0][1]), fmaxf(s[i][0][2], s[i][0][3]));
#pragma unroll
      for (int f = 1; f < 4; ++f)
        tm = fmaxf(tm, fmaxf(fmaxf(s[i][f][0], s[i][f][1]), fmaxf(s[i][f][2], s[i][f][3])));
      tm = fmaxf(tm, __shfl_xor(tm, 16));
      tm = fmaxf(tm, __shfl_xor(tm, 32));
      if (!__all(tm <= m_s[i] + 8.0f)) {   // defer-max: rescale only on real growth
        const float mnew = fmaxf(m_s[i], tm);
        const float sf = __builtin_amdgcn_exp2f(m_s[i] - mnew);
        m_s[i] = mnew;
        l_s[i] *= sf;
#pragma unroll
        for (int jd = 0; jd < 4; ++jd)
#pragma unroll
          for (int r = 0; r < 4; ++r) o_s[i][jd][r] *= sf;
      }
      float pf = 0.f;
#pragma unroll
      for (int f = 0; f < 4; ++f) {
        bf16x4v pk;
#pragma unroll
        for (int r = 0; r < 4; ++r) {
          const float p = __builtin_amdgcn_exp2f(s[i][f][r] - m_s[i]);
          pf += p;
          pk[r] = (bf16_t)p;
        }
        *(bf16x4v*)&Pb[i * 1024 + c * 64 + ((f * 16 + g * 4) ^ sc)] = pk;
      }
      l_s[i] += pf;
    }
  };

  // O^T += V^T @ P for one branch (16 MFMA)
  auto pv = [&](const bf16_t* Vt, const bf16_t* Pb, f32x4 (&o_s)[2][4]) {
    bf16x8 pa[2][2];
#pragma unroll
    for (int i = 0; i < 2; ++i) {
      pa[i][0] = *(const bf16x8*)&Pb[i * 1024 + c * 64 + ((g * 8) ^ sc)];
      pa[i][1] = *(const bf16x8*)&Pb[i * 1024 + c * 64 + ((32 + g * 8) ^ sc)];
    }
#pragma unroll
    for (int jd = 0; jd < 4; ++jd) {
      const bf16x8 v0 = *(const bf16x8*)&Vt[(jd * 16 + c) * 64 + ((g * 8) ^ sc)];
      const bf16x8 v1 = *(const bf16x8*)&Vt[(jd * 16 + c) * 64 + ((32 + g * 8) ^ sc)];
#pragma unroll
      for (int i = 0; i < 2; ++i) {
        o_s[i][jd] = __builtin_amdgcn_mfma_f32_16x16x32_bf16(v0, pa[i][0], o_s[i][jd], 0, 0, 0);
        o_s[i][jd] = __builtin_amdgcn_mfma_f32_16x16x32_bf16(v1, pa[i][1], o_s[i][jd], 0, 0, 0);
      }
    }
  };

  // prologue: stage tile 0 through registers, publish, barrier (also Mb)
  ldreg(0);
  wrlds();
  __syncthreads();

  for (int t = 0; t < 16; ++t) {
    const int kv0 = t * 64;

    // T14 issue-early: next tile's global loads ride under this tile's compute
    if (t < 15) ldreg(kv0 + 64);

    f32x4 mb[4];
#pragma unroll
    for (int f = 0; f < 4; ++f)
      mb[f] = *(const f32x4*)&Mb[kv0 + f * 16 + g * 4];

    qk_sm(Ks,  Pwv, mb, mv, lv, ov);
    qk_sm(RKs, Pwr, mb, mr, lr, orl);
    __builtin_amdgcn_s_setprio(1);
    pv(Vs,  Pwv, ov);
    pv(RVs, Pwr, orl);
    __builtin_amdgcn_s_setprio(0);

    if (t < 15) {
      __syncthreads();   // all reads of tile t done (no HBM wait)
      wrlds();           // loads long since landed; vmcnt satisfied here
      __syncthreads();   // publish tile t+1 (lgkm-only drain)
    }
  }

  // denominators: reduce per-lane partials across the 4 g-groups
#pragma unroll
  for (int i = 0; i < 2; ++i) {
    lv[i] += __shfl_xor(lv[i], 16); lv[i] += __shfl_xor(lv[i], 32);
    lr[i] += __shfl_xor(lr[i], 16); lr[i] += __shfl_xor(lr[i], 32);
  }

  bf16_t* xb = x + (size_t)b * SEQ * DMODEL + (size_t)h * DKH;
#pragma unroll
  for (int i = 0; i < 2; ++i) {
    const float rlv = 1.0f / lv[i], rlr = 1.0f / lr[i];
    const int qrow = q0 + w * 32 + i * 16 + c;
#pragma unroll
    for (int jd = 0; jd < 4; ++jd) {
      bf16x4v pk;
#pragma unroll
      for (int r = 0; r < 4; ++r)
        pk[r] = (bf16_t)(ov[i][jd][r] * rlv + orl[i][jd][r] * rlr);
      *(bf16x4v*)&xb[(size_t)qrow * DMODEL + jd * 16 + g * 4] = pk;
    }
  }
}

// ---------------- host launch ---------------------------------------------
extern "C" void kernel_launch(void* const* d_in, const int* in_sizes, int n_in,
                              void* d_out, int out_size, void* d_ws, size_t ws_size,
                              hipStream_t stream) {
  (void)in_sizes; (void)n_in; (void)out_size; (void)ws_size;
  const float* query = (const float*)d_in[0];
  const float* key_  = (const float*)d_in[1];
  const float* value = (const float*)d_in[2];
  const float* weak  = (const float*)d_in[3];
  const int*   mask  = (const int*)d_in[4];
  const float* Wq  = (const float*)d_in[5];  const float* bq  = (const float*)d_in[6];
  const float* Wk  = (const float*)d_in[7];  const float* bk  = (const float*)d_in[8];
  const float* Wv  = (const float*)d_in[9];  const float* bv  = (const float*)d_in[10];
  const float* Wrk = (const float*)d_in[11]; const float* brk = (const float*)d_in[12];
  const float* Wrv = (const float*)d_in[13]; const float* brv = (const float*)d_in[14];
  const float* Wo  = (const float*)d_in[15]; const float* bo  = (const float*)d_in[16];

  char* ws = (char*)d_ws;
  size_t off = 0;
  auto alloc = [&](size_t bytes) {
    void* p = ws + off;
    off += (bytes + 255) & ~(size_t)255;
    return p;
  };
  const size_t SZ_X = NXE * sizeof(bf16_t); // 8 MB (256-aligned -> contiguous)
  const size_t SZ_W = NWE * sizeof(bf16_t); // 2 MB

  // X segments contiguous (q,k,v,r), W segments contiguous (q,k,v,rk,rv,o),
  // proj outputs contiguous (qh,kh,rkh,vTh,rvTh).
  bf16_t* Xq = (bf16_t*)alloc(SZ_X);
  bf16_t* Xk = (bf16_t*)alloc(SZ_X);
  bf16_t* Xv = (bf16_t*)alloc(SZ_X);
  bf16_t* Xr = (bf16_t*)alloc(SZ_X);
  bf16_t* Wqb  = (bf16_t*)alloc(SZ_W);
  bf16_t* Wkb  = (bf16_t*)alloc(SZ_W);
  bf16_t* Wvb  = (bf16_t*)alloc(SZ_W);
  bf16_t* Wrkb = (bf16_t*)alloc(SZ_W);
  bf16_t* Wrvb = (bf16_t*)alloc(SZ_W);
  bf16_t* Wob  = (bf16_t*)alloc(SZ_W);
  bf16_t* qh   = (bf16_t*)alloc(SZ_X);
  bf16_t* kh   = (bf16_t*)alloc(SZ_X);
  bf16_t* rkh  = (bf16_t*)alloc(SZ_X);
  bf16_t* vTh  = (bf16_t*)alloc(SZ_X);
  bf16_t* rvTh = (bf16_t*)alloc(SZ_X);
  bf16_t* xh   = (bf16_t*)alloc(SZ_X);
  (void)Xk; (void)Xv; (void)Xr; (void)Wkb; (void)Wvb; (void)Wrkb; (void)Wrvb;
  (void)kh; (void)rkh; (void)vTh; (void)rvTh;

  // fused f32 -> bf16 (X: y 0..3 full 4096 blocks; W: y 4..9, blocks>=1024 exit)
  cvt_all<<<dim3(4096, 10), 256, 0, stream>>>(query, key_, value, weak,
                                              Wq, Wk, Wv, Wrk, Wrv, Wo,
                                              Xq, Wqb);

  // all 5 projections in one grouped dispatch (1280 blocks, 128x128 tiles)
  proj_gemm<<<dim3(1280), 256, 0, stream>>>(Xq, Wqb, qh, bq, bk, bv, brk, brv);

  // fused dual attention: 512 blocks, 68KB dynamic LDS (2 blocks/CU)
  attn_kernel<<<dim3(512), 256, 69632, stream>>>(qh, kh, rkh, vTh, rvTh, mask, xh);

  // output projection -> f32 d_out (512 blocks, 128x64 tiles, 2 blocks/CU)
  out_gemm<<<dim3(512), 256, 0, stream>>>(xh, Wob, bo, (float*)d_out);
}